// Round 1
// baseline (44082.751 us; speedup 1.0000x reference)
//
#include <hip/hip_runtime.h>

// ---------- types & helpers ----------
using short8  = __attribute__((ext_vector_type(8))) short;
using float4v = __attribute__((ext_vector_type(4))) float;

__device__ __forceinline__ unsigned short f2b(float f){
  unsigned u = __float_as_uint(f);
  u += 0x7FFFu + ((u >> 16) & 1u);
  return (unsigned short)(u >> 16);
}
__device__ __forceinline__ float b2f(unsigned short h){
  return __uint_as_float(((unsigned)h) << 16);
}
__device__ __forceinline__ float sigm(float x){ return 1.f/(1.f + __expf(-x)); }
__device__ __forceinline__ float tanh_f(float x){
  float cx = fminf(fmaxf(x, -15.f), 15.f);
  float e = __expf(2.f*cx);
  return (e - 1.f)/(e + 1.f);
}

// ---------- small prep kernels ----------
__global__ void gru_init(float* hbuf, unsigned* flags){
  int i = threadIdx.x;
  if (i < 512) hbuf[i] = 0.f;      // h buffer 0 = zeros
  if (i < 256) flags[i] = 0u;
}

__global__ void cat_hist(const float* __restrict__ a, const float* __restrict__ b,
                         unsigned short* __restrict__ d){
  int r = blockIdx.x;
  const float* ar = a + (size_t)r*512;
  const float* br = b + (size_t)r*64;
  unsigned short* dr = d + (size_t)r*576;
  for (int c = threadIdx.x; c < 576; c += 64){
    float v = (c < 512) ? ar[c] : br[c-512];
    dr[c] = f2b(v);
  }
}

// x concat with hi/lo split: [hi | lo | hi], K=1728
__global__ void cat_x3(const float* __restrict__ a, const float* __restrict__ b,
                       unsigned short* __restrict__ d){
  int r = blockIdx.x;
  const float* ar = a + (size_t)r*512;
  const float* br = b + (size_t)r*64;
  unsigned short* dr = d + (size_t)r*1728;
  for (int c = threadIdx.x; c < 576; c += 64){
    float v = (c < 512) ? ar[c] : br[c-512];
    unsigned short hi = f2b(v);
    unsigned short lo = f2b(v - b2f(hi));
    dr[c] = hi; dr[576+c] = lo; dr[1152+c] = hi;
  }
}

// w_ih split: [hi | hi | lo]  so sum gives x_hi*w_hi + x_lo*w_hi + x_hi*w_lo
__global__ void cat_w3(const float* __restrict__ w, unsigned short* __restrict__ d){
  int r = blockIdx.x;
  const float* wr_ = w + (size_t)r*576;
  unsigned short* dr = d + (size_t)r*1728;
  for (int c = threadIdx.x; c < 576; c += 64){
    float v = wr_[c];
    unsigned short hi = f2b(v);
    unsigned short lo = f2b(v - b2f(hi));
    dr[c] = hi; dr[576+c] = hi; dr[1152+c] = lo;
  }
}

__global__ void cast_bf16_k(const float* __restrict__ s, unsigned short* __restrict__ d, int n){
  int i = blockIdx.x*256 + threadIdx.x;
  if (i < n) d[i] = f2b(s[i]);
}

__global__ void transpose_k(const unsigned short* __restrict__ src,
                            unsigned short* __restrict__ dst, int R, int C){
  __shared__ unsigned short t[32][33];
  int x = threadIdx.x & 31, y = threadIdx.x >> 5;   // 256 threads: 8 rows/pass
  int r0 = blockIdx.y*32, c0 = blockIdx.x*32;
  for (int p=0;p<4;++p) t[y+p*8][x] = src[(size_t)(r0+y+p*8)*C + c0+x];
  __syncthreads();
  for (int p=0;p<4;++p) dst[(size_t)(c0+y+p*8)*R + r0+x] = t[x][y+p*8];
}

__global__ void uid_gather(const int* __restrict__ uid, const float* __restrict__ emb,
                           unsigned short* __restrict__ outcat){
  int r = blockIdx.x, e = threadIdx.x;
  outcat[(size_t)r*1088 + 1024 + e] = f2b(emb[(size_t)uid[r]*64 + e]);
}

// ---------- GEMM: C = A(MxK) * B(NxK)^T (+bias)(+tanh), bf16 in, f32 acc ----------
template<int ACT>
__global__ __launch_bounds__(256) void gemm_bt(
  const unsigned short* __restrict__ A, const unsigned short* __restrict__ B,
  const float* __restrict__ bias, float* __restrict__ Cf, unsigned short* __restrict__ Cb,
  int M, int N, int K)
{
  __shared__ unsigned short As[64*40];
  __shared__ unsigned short Bs[64*40];
  const int tid  = threadIdx.x;
  const int lane = tid & 63, wave = tid >> 6;
  const int wr = (wave>>1)*32, wc = (wave&1)*32;
  const int qa = lane>>4, la = lane&15;
  const int arow = tid>>2, acol = (tid&3)*8;
  const int tiles = K >> 5;
  const size_t abase = (size_t)(blockIdx.x*64 + arow)*K + acol;
  const size_t bbase = (size_t)(blockIdx.y*64 + arow)*K + acol;
  float4v acc[2][2] = {};
  short8 av = *(const short8*)(A + abase);
  short8 bv = *(const short8*)(B + bbase);
  for (int kt=0; kt<tiles; ++kt){
    __syncthreads();
    *(short8*)(As + arow*40 + acol) = av;
    *(short8*)(Bs + arow*40 + acol) = bv;
    __syncthreads();
    if (kt+1 < tiles){
      av = *(const short8*)(A + abase + (size_t)(kt+1)*32);
      bv = *(const short8*)(B + bbase + (size_t)(kt+1)*32);
    }
    short8 af0 = *(const short8*)(As + (wr+la)*40 + qa*8);
    short8 af1 = *(const short8*)(As + (wr+16+la)*40 + qa*8);
    short8 bf0 = *(const short8*)(Bs + (wc+la)*40 + qa*8);
    short8 bf1 = *(const short8*)(Bs + (wc+16+la)*40 + qa*8);
    acc[0][0] = __builtin_amdgcn_mfma_f32_16x16x32_bf16(af0, bf0, acc[0][0],0,0,0);
    acc[0][1] = __builtin_amdgcn_mfma_f32_16x16x32_bf16(af0, bf1, acc[0][1],0,0,0);
    acc[1][0] = __builtin_amdgcn_mfma_f32_16x16x32_bf16(af1, bf0, acc[1][0],0,0,0);
    acc[1][1] = __builtin_amdgcn_mfma_f32_16x16x32_bf16(af1, bf1, acc[1][1],0,0,0);
  }
  for (int mi=0;mi<2;++mi) for (int ni=0;ni<2;++ni){
    int n = blockIdx.y*64 + wc + ni*16 + la;
    float bvv = bias ? bias[n] : 0.f;
    for (int r=0;r<4;++r){
      int m = blockIdx.x*64 + wr + mi*16 + qa*4 + r;
      float v = acc[mi][ni][r] + bvv;
      if (ACT) v = tanh_f(v);
      if (Cf) Cf[(size_t)m*N + n] = v;
      if (Cb) Cb[(size_t)m*N + n] = f2b(v);
    }
  }
}

// ---------- GRU scan: 64 blocks x 256, per-wave flags, device-scope h exchange ----------
__global__ __launch_bounds__(256) void gru_scan(
  const float* __restrict__ gi, const float* __restrict__ whh, const float* __restrict__ bhh,
  float* hbuf, unsigned int* flags, unsigned short* __restrict__ outcat)
{
  const int lane = threadIdx.x & 63, wave = threadIdx.x >> 6;
  const int wid = blockIdx.x*4 + wave;        // 0..255
  const int j0  = blockIdx.x*8 + wave*2;      // this wave owns h[j0], h[j0+1]
  // weights: wgt[jj*3+g][m] = w_hh[g*512 + j0+jj][m*64 + lane]
  float wgt[6][8];
  #pragma unroll
  for (int jj=0; jj<2; ++jj)
    #pragma unroll
    for (int g=0; g<3; ++g)
      #pragma unroll
      for (int m=0; m<8; ++m)
        wgt[jj*3+g][m] = whh[(size_t)(g*512 + j0 + jj)*512 + m*64 + lane];
  const int myj = j0 + lane;                  // valid for lane<2
  float br=0.f, bz=0.f, bn=0.f;
  if (lane < 2){ br = bhh[myj]; bz = bhh[512+myj]; bn = bhh[1024+myj]; }

  for (int t=0; t<4096; ++t){
    float* hc = hbuf + (t&1)*512;
    float* hn = hbuf + ((t+1)&1)*512;
    // prefetch gi (independent of barrier)
    float ir=0.f, iz=0.f, inn=0.f;
    if (lane < 2){
      const float* g = gi + (size_t)t*1536;
      ir = g[myj]; iz = g[512+myj]; inn = g[1024+myj];
    }
    if (t > 0){
      const unsigned tgt = (unsigned)t;
      for(;;){
        unsigned f0 = __hip_atomic_load(flags + lane*4+0, __ATOMIC_RELAXED, __HIP_MEMORY_SCOPE_AGENT);
        unsigned f1 = __hip_atomic_load(flags + lane*4+1, __ATOMIC_RELAXED, __HIP_MEMORY_SCOPE_AGENT);
        unsigned f2 = __hip_atomic_load(flags + lane*4+2, __ATOMIC_RELAXED, __HIP_MEMORY_SCOPE_AGENT);
        unsigned f3 = __hip_atomic_load(flags + lane*4+3, __ATOMIC_RELAXED, __HIP_MEMORY_SCOPE_AGENT);
        unsigned mn = min(min(f0,f1), min(f2,f3));
        if (__all(mn >= tgt)) break;
      }
      __builtin_amdgcn_fence(__ATOMIC_ACQUIRE, "agent");
    }
    float hprev = 0.f;
    if (lane < 2) hprev = __hip_atomic_load(hc + myj, __ATOMIC_RELAXED, __HIP_MEMORY_SCOPE_AGENT);
    float s0=0,s1=0,s2=0,s3=0,s4=0,s5=0;
    #pragma unroll
    for (int m=0;m<8;++m){
      float h = __hip_atomic_load(hc + m*64 + lane, __ATOMIC_RELAXED, __HIP_MEMORY_SCOPE_AGENT);
      s0 += wgt[0][m]*h; s1 += wgt[1][m]*h; s2 += wgt[2][m]*h;
      s3 += wgt[3][m]*h; s4 += wgt[4][m]*h; s5 += wgt[5][m]*h;
    }
    #pragma unroll
    for (int d=1; d<64; d<<=1){
      s0 += __shfl_xor(s0,d,64); s1 += __shfl_xor(s1,d,64); s2 += __shfl_xor(s2,d,64);
      s3 += __shfl_xor(s3,d,64); s4 += __shfl_xor(s4,d,64); s5 += __shfl_xor(s5,d,64);
    }
    if (lane < 2){
      float sr = lane ? s3 : s0;
      float sz = lane ? s4 : s1;
      float sn = lane ? s5 : s2;
      float r = sigm(ir + sr + br);
      float z = sigm(iz + sz + bz);
      float n = tanh_f(inn + r*(sn + bn));
      float hv = (1.f - z)*n + z*hprev;
      __hip_atomic_store(hn + myj, hv, __ATOMIC_RELAXED, __HIP_MEMORY_SCOPE_AGENT);
      if (t >= 2048) outcat[(size_t)(t-2048)*1088 + myj] = f2b(hv);
    }
    __builtin_amdgcn_fence(__ATOMIC_RELEASE, "agent");
    if (lane == 0)
      __hip_atomic_store(flags + wid, (unsigned)(t+1), __ATOMIC_RELAXED, __HIP_MEMORY_SCOPE_AGENT);
  }
}

// ---------- attention pass 1: per-row max & sumexp (split over 16) ----------
__global__ __launch_bounds__(256) void attn_stats(
  const unsigned short* __restrict__ Q, const unsigned short* __restrict__ H,
  float* __restrict__ mpart, float* __restrict__ lpart)
{
  __shared__ unsigned short qs[64*520];
  const int tid = threadIdx.x;
  const int lane = tid&63, wave = tid>>6;
  const int qa = lane>>4, la = lane&15;
  const int qt = blockIdx.x, sp = blockIdx.y;
  for (int p=0;p<16;++p){
    int idx = p*256 + tid;
    int row = idx>>6, c8 = (idx&63)*8;
    *(short8*)(qs + row*520 + c8) = *(const short8*)(Q + (size_t)(qt*64+row)*1088 + c8);
  }
  __syncthreads();
  const int rowbase = wave*16;
  float mrun[4] = {-3e38f,-3e38f,-3e38f,-3e38f};
  float lrun[4] = {0.f,0.f,0.f,0.f};
  for (int c=0;c<32;++c){
    int hb = sp*2048 + c*64;
    float4v sacc[4] = {};
    for (int ks=0; ks<16; ++ks){
      short8 af = *(const short8*)(qs + (rowbase+la)*520 + ks*32 + qa*8);
      #pragma unroll
      for (int ni=0; ni<4; ++ni){
        short8 bf = *(const short8*)(H + (size_t)(hb + ni*16 + la)*512 + ks*32 + qa*8);
        sacc[ni] = __builtin_amdgcn_mfma_f32_16x16x32_bf16(af, bf, sacc[ni],0,0,0);
      }
    }
    #pragma unroll
    for (int r=0;r<4;++r){
      float cm = fmaxf(fmaxf(sacc[0][r],sacc[1][r]), fmaxf(sacc[2][r],sacc[3][r]));
      cm = fmaxf(cm, __shfl_xor(cm,1,64));
      cm = fmaxf(cm, __shfl_xor(cm,2,64));
      cm = fmaxf(cm, __shfl_xor(cm,4,64));
      cm = fmaxf(cm, __shfl_xor(cm,8,64));
      float mnew = fmaxf(mrun[r], cm);
      float ls = __expf(sacc[0][r]-mnew)+__expf(sacc[1][r]-mnew)
               + __expf(sacc[2][r]-mnew)+__expf(sacc[3][r]-mnew);
      ls += __shfl_xor(ls,1,64); ls += __shfl_xor(ls,2,64);
      ls += __shfl_xor(ls,4,64); ls += __shfl_xor(ls,8,64);
      lrun[r] = lrun[r]*__expf(mrun[r]-mnew) + ls;
      mrun[r] = mnew;
    }
  }
  if (la == 0){
    #pragma unroll
    for (int r=0;r<4;++r){
      int row = qt*64 + rowbase + qa*4 + r;
      mpart[sp*2048 + row] = mrun[r];
      lpart[sp*2048 + row] = lrun[r];
    }
  }
}

__global__ void stats_combine(const float* __restrict__ mpart, const float* __restrict__ lpart,
                              float* __restrict__ mrow, float* __restrict__ lrow){
  int r = blockIdx.x*64 + threadIdx.x;
  float m = -3e38f;
  for (int s=0;s<16;++s) m = fmaxf(m, mpart[s*2048 + r]);
  float l = 0.f;
  for (int s=0;s<16;++s) l += lpart[s*2048 + r]*__expf(mpart[s*2048 + r] - m);
  mrow[r] = m; lrow[r] = l;
}

// ---------- attention pass 2: context partials (split over 8) ----------
__global__ __launch_bounds__(256) void attn_ctx(
  const unsigned short* __restrict__ Q, const unsigned short* __restrict__ H,
  const unsigned short* __restrict__ Ht, const float* __restrict__ mrow,
  float* __restrict__ ctxpart)
{
  __shared__ unsigned short qs[64*520];
  __shared__ unsigned short ps[4*16*80];
  const int tid = threadIdx.x;
  const int lane = tid&63, wave = tid>>6;
  const int qa = lane>>4, la = lane&15;
  const int qt = blockIdx.x, sp = blockIdx.y;
  for (int p=0;p<16;++p){
    int idx = p*256 + tid;
    int row = idx>>6, c8 = (idx&63)*8;
    *(short8*)(qs + row*520 + c8) = *(const short8*)(Q + (size_t)(qt*64+row)*1088 + c8);
  }
  __syncthreads();
  const int rowbase = wave*16;
  float mreg[4];
  #pragma unroll
  for (int r=0;r<4;++r) mreg[r] = mrow[qt*64 + rowbase + qa*4 + r];
  float4v cacc[32] = {};
  unsigned short* pw = ps + wave*16*80;
  for (int c=0;c<64;++c){
    int hb = sp*4096 + c*64;
    float4v sacc[4] = {};
    for (int ks=0; ks<16; ++ks){
      short8 af = *(const short8*)(qs + (rowbase+la)*520 + ks*32 + qa*8);
      #pragma unroll
      for (int ni=0; ni<4; ++ni){
        short8 bf = *(const short8*)(H + (size_t)(hb + ni*16 + la)*512 + ks*32 + qa*8);
        sacc[ni] = __builtin_amdgcn_mfma_f32_16x16x32_bf16(af, bf, sacc[ni],0,0,0);
      }
    }
    // P = exp(S - m): C-layout -> LDS (row-major) for A-operand reads
    #pragma unroll
    for (int ni=0;ni<4;++ni)
      #pragma unroll
      for (int r=0;r<4;++r)
        pw[(qa*4+r)*80 + ni*16 + la] = f2b(__expf(sacc[ni][r]-mreg[r]));
    #pragma unroll
    for (int ks2=0; ks2<2; ++ks2){
      short8 paf = *(const short8*)(pw + la*80 + ks2*32 + qa*8);
      for (int f=0; f<32; ++f){
        short8 bf = *(const short8*)(Ht + (size_t)(f*16+la)*32768 + hb + ks2*32 + qa*8);
        cacc[f] = __builtin_amdgcn_mfma_f32_16x16x32_bf16(paf, bf, cacc[f],0,0,0);
      }
    }
  }
  for (int f=0; f<32; ++f)
    #pragma unroll
    for (int r=0;r<4;++r){
      int row = qt*64 + rowbase + qa*4 + r;
      ctxpart[((size_t)sp*2048 + row)*512 + f*16 + la] = cacc[f][r];
    }
}

__global__ void ctx_reduce(const float* __restrict__ ctxpart, const float* __restrict__ lrow,
                           unsigned short* __restrict__ outcat){
  int idx = blockIdx.x*256 + threadIdx.x;
  int r = idx >> 9, cc = idx & 511;
  float s = 0.f;
  for (int sp=0; sp<8; ++sp) s += ctxpart[((size_t)sp*2048 + r)*512 + cc];
  outcat[(size_t)r*1088 + 512 + cc] = f2b(s / lrow[r]);
}

__global__ void log_softmax_k(const float* __restrict__ y, float* __restrict__ out){
  int r = blockIdx.x, lane = threadIdx.x;
  const float* yr = y + (size_t)r*512;
  float v[8]; float m = -3e38f;
  #pragma unroll
  for (int i=0;i<8;++i){ v[i] = yr[lane + 64*i]; m = fmaxf(m, v[i]); }
  #pragma unroll
  for (int d=1; d<64; d<<=1) m = fmaxf(m, __shfl_xor(m,d,64));
  float s = 0.f;
  #pragma unroll
  for (int i=0;i<8;++i) s += __expf(v[i]-m);
  #pragma unroll
  for (int d=1; d<64; d<<=1) s += __shfl_xor(s,d,64);
  float ls = __logf(s) + m;
  float* orow = out + (size_t)r*512;
  #pragma unroll
  for (int i=0;i<8;++i) orow[lane + 64*i] = v[i] - ls;
}

// ---------- launcher ----------
extern "C" void kernel_launch(void* const* d_in, const int* in_sizes, int n_in,
                              void* d_out, int out_size, void* d_ws, size_t ws_size,
                              hipStream_t stream)
{
  const float* loc  = (const float*)d_in[0];
  const float* tim  = (const float*)d_in[1];
  const float* hloc = (const float*)d_in[2];
  const float* htim = (const float*)d_in[3];
  const int*   uid  = (const int*)d_in[5];
  const float* fc_attn_w  = (const float*)d_in[8];
  const float* fc_attn_b  = (const float*)d_in[9];
  const float* w_ih = (const float*)d_in[10];
  const float* w_hh = (const float*)d_in[11];
  const float* b_ih = (const float*)d_in[12];
  const float* b_hh = (const float*)d_in[13];
  const float* emb_uid    = (const float*)d_in[14];
  const float* fc_final_w = (const float*)d_in[15];
  const float* fc_final_b = (const float*)d_in[16];
  float* out = (float*)d_out;

  char* ws = (char*)d_ws;
  size_t off = 0;
  auto alloc = [&](size_t b){ size_t o = off; off = (off + b + 255) & ~(size_t)255; return o; };
  size_t o_xcat3 = alloc(4096ULL*1728*2);    // also aliased as y (4 MB) after gi GEMM
  size_t o_hist  = alloc(32768ULL*576*2);    // aliased as ctxpart after history GEMM
  size_t o_wAb   = alloc(512ULL*576*2);
  size_t o_wIb3  = alloc(1536ULL*1728*2);
  size_t o_wFb   = alloc(512ULL*1088*2);
  size_t o_H     = alloc(32768ULL*512*2);
  size_t o_Ht    = alloc(32768ULL*512*2);
  size_t o_gi    = alloc(4096ULL*1536*4);
  size_t o_outc  = alloc(2048ULL*1088*2);
  size_t o_hbuf  = alloc(1024*4);
  size_t o_flags = alloc(256*4);
  size_t o_mp    = alloc(16*2048*4);
  size_t o_lp    = alloc(16*2048*4);
  size_t o_mr    = alloc(2048*4);
  size_t o_lr    = alloc(2048*4);
  (void)ws_size; (void)in_sizes; (void)n_in; (void)out_size;

  unsigned short* xcat3   = (unsigned short*)(ws + o_xcat3);
  unsigned short* histcat = (unsigned short*)(ws + o_hist);
  unsigned short* wAb     = (unsigned short*)(ws + o_wAb);
  unsigned short* wIb3    = (unsigned short*)(ws + o_wIb3);
  unsigned short* wFb     = (unsigned short*)(ws + o_wFb);
  unsigned short* Hb      = (unsigned short*)(ws + o_H);
  unsigned short* Htb     = (unsigned short*)(ws + o_Ht);
  float*          gi      = (float*)(ws + o_gi);
  unsigned short* outc    = (unsigned short*)(ws + o_outc);
  float*          hbuf    = (float*)(ws + o_hbuf);
  unsigned*       flags   = (unsigned*)(ws + o_flags);
  float*          mp      = (float*)(ws + o_mp);
  float*          lp      = (float*)(ws + o_lp);
  float*          mr      = (float*)(ws + o_mr);
  float*          lr      = (float*)(ws + o_lr);
  float*          y       = (float*)(ws + o_xcat3);   // alias
  float*          ctxpart = (float*)(ws + o_hist);    // alias

  gru_init<<<1, 512, 0, stream>>>(hbuf, flags);
  cat_x3<<<4096, 64, 0, stream>>>(loc, tim, xcat3);
  cat_hist<<<32768, 64, 0, stream>>>(hloc, htim, histcat);
  cast_bf16_k<<<(294912+255)/256, 256, 0, stream>>>(fc_attn_w, wAb, 294912);
  cat_w3<<<1536, 64, 0, stream>>>(w_ih, wIb3);
  cast_bf16_k<<<(557056+255)/256, 256, 0, stream>>>(fc_final_w, wFb, 557056);

  // history = tanh(histcat @ fc_attn_w^T + b) -> bf16 H
  gemm_bt<1><<<dim3(512,8), 256, 0, stream>>>(histcat, wAb, fc_attn_b, nullptr, Hb, 32768, 512, 576);
  transpose_k<<<dim3(16,1024), 256, 0, stream>>>(Hb, Htb, 32768, 512);
  // gi = x @ w_ih^T + b_ih (hi/lo split, K=1728) -> fp32
  gemm_bt<0><<<dim3(64,24), 256, 0, stream>>>(xcat3, wIb3, b_ih, gi, nullptr, 4096, 1536, 1728);
  // sequential GRU over 4096 steps; writes q (bf16) into outcat cols 0..511
  gru_scan<<<64, 256, 0, stream>>>(gi, w_hh, b_hh, hbuf, flags, outc);
  // softmax stats
  attn_stats<<<dim3(32,16), 256, 0, stream>>>(outc, Hb, mp, lp);
  stats_combine<<<32, 64, 0, stream>>>(mp, lp, mr, lr);
  // context partials + reduce (writes outcat cols 512..1023)
  attn_ctx<<<dim3(32,8), 256, 0, stream>>>(outc, Hb, Htb, mr, ctxpart);
  ctx_reduce<<<4096, 256, 0, stream>>>(ctxpart, lr, outc);
  // uid embedding (outcat cols 1024..1087)
  uid_gather<<<2048, 64, 0, stream>>>(uid, emb_uid, outc);
  // final linear + log_softmax
  gemm_bt<0><<<dim3(32,8), 256, 0, stream>>>(outc, wFb, fc_final_b, y, nullptr, 2048, 512, 1088);
  log_softmax_k<<<2048, 64, 0, stream>>>(y, out);
}

// Round 2
// 25032.753 us; speedup vs baseline: 1.7610x; 1.7610x over previous
//
#include <hip/hip_runtime.h>

// ---------- types & helpers ----------
using short8  = __attribute__((ext_vector_type(8))) short;
using float4v = __attribute__((ext_vector_type(4))) float;

__device__ __forceinline__ unsigned short f2b(float f){
  unsigned u = __float_as_uint(f);
  u += 0x7FFFu + ((u >> 16) & 1u);
  return (unsigned short)(u >> 16);
}
__device__ __forceinline__ float b2f(unsigned short h){
  return __uint_as_float(((unsigned)h) << 16);
}
__device__ __forceinline__ float sigm(float x){ return 1.f/(1.f + __expf(-x)); }
__device__ __forceinline__ float tanh_f(float x){
  float cx = fminf(fmaxf(x, -15.f), 15.f);
  float e = __expf(2.f*cx);
  return (e - 1.f)/(e + 1.f);
}

// ---------- small prep kernels ----------
__global__ void gru_init(float* hbuf, unsigned* flags){
  int i = threadIdx.x;
  if (i < 1024) hbuf[i] = 0.f;     // both h ping-pong buffers = zeros
  if (i < 512) flags[i] = 0u;      // 32 flags padded to 64B stride
}

__global__ void cat_hist(const float* __restrict__ a, const float* __restrict__ b,
                         unsigned short* __restrict__ d){
  int r = blockIdx.x;
  const float* ar = a + (size_t)r*512;
  const float* br = b + (size_t)r*64;
  unsigned short* dr = d + (size_t)r*576;
  for (int c = threadIdx.x; c < 576; c += 64){
    float v = (c < 512) ? ar[c] : br[c-512];
    dr[c] = f2b(v);
  }
}

// x concat with hi/lo split: [hi | lo | hi], K=1728
__global__ void cat_x3(const float* __restrict__ a, const float* __restrict__ b,
                       unsigned short* __restrict__ d){
  int r = blockIdx.x;
  const float* ar = a + (size_t)r*512;
  const float* br = b + (size_t)r*64;
  unsigned short* dr = d + (size_t)r*1728;
  for (int c = threadIdx.x; c < 576; c += 64){
    float v = (c < 512) ? ar[c] : br[c-512];
    unsigned short hi = f2b(v);
    unsigned short lo = f2b(v - b2f(hi));
    dr[c] = hi; dr[576+c] = lo; dr[1152+c] = hi;
  }
}

// w_ih split: [hi | hi | lo]  so sum gives x_hi*w_hi + x_lo*w_hi + x_hi*w_lo
__global__ void cat_w3(const float* __restrict__ w, unsigned short* __restrict__ d){
  int r = blockIdx.x;
  const float* wr_ = w + (size_t)r*576;
  unsigned short* dr = d + (size_t)r*1728;
  for (int c = threadIdx.x; c < 576; c += 64){
    float v = wr_[c];
    unsigned short hi = f2b(v);
    unsigned short lo = f2b(v - b2f(hi));
    dr[c] = hi; dr[576+c] = hi; dr[1152+c] = lo;
  }
}

__global__ void cast_bf16_k(const float* __restrict__ s, unsigned short* __restrict__ d, int n){
  int i = blockIdx.x*256 + threadIdx.x;
  if (i < n) d[i] = f2b(s[i]);
}

__global__ void transpose_k(const unsigned short* __restrict__ src,
                            unsigned short* __restrict__ dst, int R, int C){
  __shared__ unsigned short t[32][33];
  int x = threadIdx.x & 31, y = threadIdx.x >> 5;   // 256 threads: 8 rows/pass
  int r0 = blockIdx.y*32, c0 = blockIdx.x*32;
  for (int p=0;p<4;++p) t[y+p*8][x] = src[(size_t)(r0+y+p*8)*C + c0+x];
  __syncthreads();
  for (int p=0;p<4;++p) dst[(size_t)(c0+y+p*8)*R + r0+x] = t[x][y+p*8];
}

__global__ void uid_gather(const int* __restrict__ uid, const float* __restrict__ emb,
                           unsigned short* __restrict__ outcat){
  int r = blockIdx.x, e = threadIdx.x;
  outcat[(size_t)r*1088 + 1024 + e] = f2b(emb[(size_t)uid[r]*64 + e]);
}

// ---------- GEMM: C = A(MxK) * B(NxK)^T (+bias)(+tanh), bf16 in, f32 acc ----------
template<int ACT>
__global__ __launch_bounds__(256) void gemm_bt(
  const unsigned short* __restrict__ A, const unsigned short* __restrict__ B,
  const float* __restrict__ bias, float* __restrict__ Cf, unsigned short* __restrict__ Cb,
  int M, int N, int K)
{
  __shared__ unsigned short As[64*40];
  __shared__ unsigned short Bs[64*40];
  const int tid  = threadIdx.x;
  const int lane = tid & 63, wave = tid >> 6;
  const int wr = (wave>>1)*32, wc = (wave&1)*32;
  const int qa = lane>>4, la = lane&15;
  const int arow = tid>>2, acol = (tid&3)*8;
  const int tiles = K >> 5;
  const size_t abase = (size_t)(blockIdx.x*64 + arow)*K + acol;
  const size_t bbase = (size_t)(blockIdx.y*64 + arow)*K + acol;
  float4v acc[2][2] = {};
  short8 av = *(const short8*)(A + abase);
  short8 bv = *(const short8*)(B + bbase);
  for (int kt=0; kt<tiles; ++kt){
    __syncthreads();
    *(short8*)(As + arow*40 + acol) = av;
    *(short8*)(Bs + arow*40 + acol) = bv;
    __syncthreads();
    if (kt+1 < tiles){
      av = *(const short8*)(A + abase + (size_t)(kt+1)*32);
      bv = *(const short8*)(B + bbase + (size_t)(kt+1)*32);
    }
    short8 af0 = *(const short8*)(As + (wr+la)*40 + qa*8);
    short8 af1 = *(const short8*)(As + (wr+16+la)*40 + qa*8);
    short8 bf0 = *(const short8*)(Bs + (wc+la)*40 + qa*8);
    short8 bf1 = *(const short8*)(Bs + (wc+16+la)*40 + qa*8);
    acc[0][0] = __builtin_amdgcn_mfma_f32_16x16x32_bf16(af0, bf0, acc[0][0],0,0,0);
    acc[0][1] = __builtin_amdgcn_mfma_f32_16x16x32_bf16(af0, bf1, acc[0][1],0,0,0);
    acc[1][0] = __builtin_amdgcn_mfma_f32_16x16x32_bf16(af1, bf0, acc[1][0],0,0,0);
    acc[1][1] = __builtin_amdgcn_mfma_f32_16x16x32_bf16(af1, bf1, acc[1][1],0,0,0);
  }
  for (int mi=0;mi<2;++mi) for (int ni=0;ni<2;++ni){
    int n = blockIdx.y*64 + wc + ni*16 + la;
    float bvv = bias ? bias[n] : 0.f;
    for (int r=0;r<4;++r){
      int m = blockIdx.x*64 + wr + mi*16 + qa*4 + r;
      float v = acc[mi][ni][r] + bvv;
      if (ACT) v = tanh_f(v);
      if (Cf) Cf[(size_t)m*N + n] = v;
      if (Cb) Cb[(size_t)m*N + n] = f2b(v);
    }
  }
}

// ---------- GRU scan: 32 blocks x 512 threads ----------
// Block b owns h outputs [b*16, b*16+16). Wave w owns outputs b*16+w*2+{0,1}.
// Lane covers h columns [8*lane, 8*lane+8). Rows (3 gates x 2 outs) -> 6 slots,
// reduce-scatter tree leaves slot (lane&7)'s full sum in each lane.
__global__ __launch_bounds__(512) void gru_scan(
  const float* __restrict__ gi, const float* __restrict__ whh, const float* __restrict__ bhh,
  float* hbuf, unsigned int* flags, unsigned short* __restrict__ outcat)
{
  const int tid  = threadIdx.x;
  const int lane = tid & 63, wave = tid >> 6;
  const int blk  = blockIdx.x;
  const int obase = blk*16 + wave*2;          // this wave's 2 outputs
  // weights: wgt[s][m] = w_hh[g*512 + obase + q][lane*8 + m], s = g*2+q
  float wgt[6][8];
  #pragma unroll
  for (int s=0; s<6; ++s){
    int g = s >> 1, q = s & 1;
    const float* wr_ = whh + (size_t)(g*512 + obase + q)*512 + lane*8;
    #pragma unroll
    for (int m=0; m<8; ++m) wgt[s][m] = wr_[m];
  }
  const int myj = obase + lane;               // valid for lane<2
  float br=0.f, bz=0.f, bn=0.f;
  if (lane < 2){ br = bhh[myj]; bz = bhh[512+myj]; bn = bhh[1024+myj]; }

  auto red = [&](float a, float b, int bit, int d) -> float {
    float kept = bit ? b : a;
    float sent = bit ? a : b;
    float recv = __shfl_xor(sent, d, 64);
    return kept + recv;
  };
  const int bit0 = lane & 1, bit1 = (lane>>1)&1, bit2 = (lane>>2)&1;

  for (int t=0; t<4096; ++t){
    float* hc = hbuf + (t&1)*512;
    float* hn = hbuf + ((t+1)&1)*512;
    // prefetch gi (independent of the flag wait)
    float ir=0.f, iz=0.f, inn=0.f;
    if (lane < 2){
      const float* g = gi + (size_t)t*1536;
      ir = g[myj]; iz = g[512+myj]; inn = g[1024+myj];
    }
    if (t > 0){
      const unsigned tgt = (unsigned)t;
      const unsigned* fp = flags + (lane & 31)*16;   // 32 flags on 64B lines
      for(;;){
        unsigned f = __hip_atomic_load(fp, __ATOMIC_RELAXED, __HIP_MEMORY_SCOPE_AGENT);
        if (__all(f >= tgt)) break;
      }
      __builtin_amdgcn_fence(__ATOMIC_ACQUIRE, "agent");
    }
    // load h: lane covers cols 8*lane..8*lane+7 as 4x u64 atomic loads
    const unsigned long long* hc64 = (const unsigned long long*)hc + lane*4;
    unsigned long long a0 = __hip_atomic_load(hc64+0, __ATOMIC_RELAXED, __HIP_MEMORY_SCOPE_AGENT);
    unsigned long long a1 = __hip_atomic_load(hc64+1, __ATOMIC_RELAXED, __HIP_MEMORY_SCOPE_AGENT);
    unsigned long long a2 = __hip_atomic_load(hc64+2, __ATOMIC_RELAXED, __HIP_MEMORY_SCOPE_AGENT);
    unsigned long long a3 = __hip_atomic_load(hc64+3, __ATOMIC_RELAXED, __HIP_MEMORY_SCOPE_AGENT);
    float hprev = 0.f;
    if (lane < 2) hprev = __hip_atomic_load(hc + myj, __ATOMIC_RELAXED, __HIP_MEMORY_SCOPE_AGENT);
    float hv[8];
    hv[0]=__uint_as_float((unsigned)a0); hv[1]=__uint_as_float((unsigned)(a0>>32));
    hv[2]=__uint_as_float((unsigned)a1); hv[3]=__uint_as_float((unsigned)(a1>>32));
    hv[4]=__uint_as_float((unsigned)a2); hv[5]=__uint_as_float((unsigned)(a2>>32));
    hv[6]=__uint_as_float((unsigned)a3); hv[7]=__uint_as_float((unsigned)(a3>>32));
    float p0=0,p1=0,p2=0,p3=0,p4=0,p5=0;
    #pragma unroll
    for (int m=0; m<8; ++m){
      float h = hv[m];
      p0 += wgt[0][m]*h; p1 += wgt[1][m]*h; p2 += wgt[2][m]*h;
      p3 += wgt[3][m]*h; p4 += wgt[4][m]*h; p5 += wgt[5][m]*h;
    }
    // reduce-scatter: final v = full sum of slot (lane&7)
    float q0 = red(p0,p1,bit0,1);
    float q1 = red(p2,p3,bit0,1);
    float q2 = red(p4,p5,bit0,1);
    float q3 = 0.f;
    float r0 = red(q0,q1,bit1,2);
    float r1 = red(q2,q3,bit1,2);
    float v  = red(r0,r1,bit2,4);
    v += __shfl_xor(v, 8, 64);
    v += __shfl_xor(v, 16, 64);
    v += __shfl_xor(v, 32, 64);
    // slot layout: 0,1 = r gates; 2,3 = z; 4,5 = n  (for outputs q=0,1)
    float sz = __shfl(v, lane+2, 64);
    float sn = __shfl(v, lane+4, 64);
    if (lane < 2){
      float r = sigm(ir + v + br);
      float z = sigm(iz + sz + bz);
      float n = tanh_f(inn + r*(sn + bn));
      float hval = (1.f - z)*n + z*hprev;
      float other = __shfl(hval, 1, 64);   // lane1's value into lane0
      if (lane == 0){
        unsigned long long pack = (unsigned long long)__float_as_uint(hval)
                                | ((unsigned long long)__float_as_uint(other) << 32);
        __hip_atomic_store((unsigned long long*)hn + (obase>>1), pack,
                           __ATOMIC_RELAXED, __HIP_MEMORY_SCOPE_AGENT);
        if (t >= 2048){
          unsigned opack = (unsigned)f2b(hval) | ((unsigned)f2b(other) << 16);
          *(unsigned*)(outcat + (size_t)(t-2048)*1088 + obase) = opack;
        }
      }
    }
    __builtin_amdgcn_fence(__ATOMIC_RELEASE, "agent");
    __syncthreads();
    if (tid == 0)
      __hip_atomic_store(flags + blk*16, (unsigned)(t+1),
                         __ATOMIC_RELAXED, __HIP_MEMORY_SCOPE_AGENT);
  }
}

// ---------- attention pass 1: per-row max & sumexp (split over 16) ----------
__global__ __launch_bounds__(256) void attn_stats(
  const unsigned short* __restrict__ Q, const unsigned short* __restrict__ H,
  float* __restrict__ mpart, float* __restrict__ lpart)
{
  __shared__ unsigned short qs[64*520];
  const int tid = threadIdx.x;
  const int lane = tid&63, wave = tid>>6;
  const int qa = lane>>4, la = lane&15;
  const int qt = blockIdx.x, sp = blockIdx.y;
  for (int p=0;p<16;++p){
    int idx = p*256 + tid;
    int row = idx>>6, c8 = (idx&63)*8;
    *(short8*)(qs + row*520 + c8) = *(const short8*)(Q + (size_t)(qt*64+row)*1088 + c8);
  }
  __syncthreads();
  const int rowbase = wave*16;
  float mrun[4] = {-3e38f,-3e38f,-3e38f,-3e38f};
  float lrun[4] = {0.f,0.f,0.f,0.f};
  for (int c=0;c<32;++c){
    int hb = sp*2048 + c*64;
    float4v sacc[4] = {};
    for (int ks=0; ks<16; ++ks){
      short8 af = *(const short8*)(qs + (rowbase+la)*520 + ks*32 + qa*8);
      #pragma unroll
      for (int ni=0; ni<4; ++ni){
        short8 bf = *(const short8*)(H + (size_t)(hb + ni*16 + la)*512 + ks*32 + qa*8);
        sacc[ni] = __builtin_amdgcn_mfma_f32_16x16x32_bf16(af, bf, sacc[ni],0,0,0);
      }
    }
    #pragma unroll
    for (int r=0;r<4;++r){
      float cm = fmaxf(fmaxf(sacc[0][r],sacc[1][r]), fmaxf(sacc[2][r],sacc[3][r]));
      cm = fmaxf(cm, __shfl_xor(cm,1,64));
      cm = fmaxf(cm, __shfl_xor(cm,2,64));
      cm = fmaxf(cm, __shfl_xor(cm,4,64));
      cm = fmaxf(cm, __shfl_xor(cm,8,64));
      float mnew = fmaxf(mrun[r], cm);
      float ls = __expf(sacc[0][r]-mnew)+__expf(sacc[1][r]-mnew)
               + __expf(sacc[2][r]-mnew)+__expf(sacc[3][r]-mnew);
      ls += __shfl_xor(ls,1,64); ls += __shfl_xor(ls,2,64);
      ls += __shfl_xor(ls,4,64); ls += __shfl_xor(ls,8,64);
      lrun[r] = lrun[r]*__expf(mrun[r]-mnew) + ls;
      mrun[r] = mnew;
    }
  }
  if (la == 0){
    #pragma unroll
    for (int r=0;r<4;++r){
      int row = qt*64 + rowbase + qa*4 + r;
      mpart[sp*2048 + row] = mrun[r];
      lpart[sp*2048 + row] = lrun[r];
    }
  }
}

__global__ void stats_combine(const float* __restrict__ mpart, const float* __restrict__ lpart,
                              float* __restrict__ mrow, float* __restrict__ lrow){
  int r = blockIdx.x*64 + threadIdx.x;
  float m = -3e38f;
  for (int s=0;s<16;++s) m = fmaxf(m, mpart[s*2048 + r]);
  float l = 0.f;
  for (int s=0;s<16;++s) l += lpart[s*2048 + r]*__expf(mpart[s*2048 + r] - m);
  mrow[r] = m; lrow[r] = l;
}

// ---------- attention pass 2: context partials (split over 8) ----------
__global__ __launch_bounds__(256) void attn_ctx(
  const unsigned short* __restrict__ Q, const unsigned short* __restrict__ H,
  const unsigned short* __restrict__ Ht, const float* __restrict__ mrow,
  float* __restrict__ ctxpart)
{
  __shared__ unsigned short qs[64*520];
  __shared__ unsigned short ps[4*16*80];
  const int tid = threadIdx.x;
  const int lane = tid&63, wave = tid>>6;
  const int qa = lane>>4, la = lane&15;
  const int qt = blockIdx.x, sp = blockIdx.y;
  for (int p=0;p<16;++p){
    int idx = p*256 + tid;
    int row = idx>>6, c8 = (idx&63)*8;
    *(short8*)(qs + row*520 + c8) = *(const short8*)(Q + (size_t)(qt*64+row)*1088 + c8);
  }
  __syncthreads();
  const int rowbase = wave*16;
  float mreg[4];
  #pragma unroll
  for (int r=0;r<4;++r) mreg[r] = mrow[qt*64 + rowbase + qa*4 + r];
  float4v cacc[32] = {};
  unsigned short* pw = ps + wave*16*80;
  for (int c=0;c<64;++c){
    int hb = sp*4096 + c*64;
    float4v sacc[4] = {};
    for (int ks=0; ks<16; ++ks){
      short8 af = *(const short8*)(qs + (rowbase+la)*520 + ks*32 + qa*8);
      #pragma unroll
      for (int ni=0; ni<4; ++ni){
        short8 bf = *(const short8*)(H + (size_t)(hb + ni*16 + la)*512 + ks*32 + qa*8);
        sacc[ni] = __builtin_amdgcn_mfma_f32_16x16x32_bf16(af, bf, sacc[ni],0,0,0);
      }
    }
    #pragma unroll
    for (int ni=0;ni<4;++ni)
      #pragma unroll
      for (int r=0;r<4;++r)
        pw[(qa*4+r)*80 + ni*16 + la] = f2b(__expf(sacc[ni][r]-mreg[r]));
    #pragma unroll
    for (int ks2=0; ks2<2; ++ks2){
      short8 paf = *(const short8*)(pw + la*80 + ks2*32 + qa*8);
      for (int f=0; f<32; ++f){
        short8 bf = *(const short8*)(Ht + (size_t)(f*16+la)*32768 + hb + ks2*32 + qa*8);
        cacc[f] = __builtin_amdgcn_mfma_f32_16x16x32_bf16(paf, bf, cacc[f],0,0,0);
      }
    }
  }
  for (int f=0; f<32; ++f)
    #pragma unroll
    for (int r=0;r<4;++r){
      int row = qt*64 + rowbase + qa*4 + r;
      ctxpart[((size_t)sp*2048 + row)*512 + f*16 + la] = cacc[f][r];
    }
}

__global__ void ctx_reduce(const float* __restrict__ ctxpart, const float* __restrict__ lrow,
                           unsigned short* __restrict__ outcat){
  int idx = blockIdx.x*256 + threadIdx.x;
  int r = idx >> 9, cc = idx & 511;
  float s = 0.f;
  for (int sp=0; sp<8; ++sp) s += ctxpart[((size_t)sp*2048 + r)*512 + cc];
  outcat[(size_t)r*1088 + 512 + cc] = f2b(s / lrow[r]);
}

__global__ void log_softmax_k(const float* __restrict__ y, float* __restrict__ out){
  int r = blockIdx.x, lane = threadIdx.x;
  const float* yr = y + (size_t)r*512;
  float v[8]; float m = -3e38f;
  #pragma unroll
  for (int i=0;i<8;++i){ v[i] = yr[lane + 64*i]; m = fmaxf(m, v[i]); }
  #pragma unroll
  for (int d=1; d<64; d<<=1) m = fmaxf(m, __shfl_xor(m,d,64));
  float s = 0.f;
  #pragma unroll
  for (int i=0;i<8;++i) s += __expf(v[i]-m);
  #pragma unroll
  for (int d=1; d<64; d<<=1) s += __shfl_xor(s,d,64);
  float ls = __logf(s) + m;
  float* orow = out + (size_t)r*512;
  #pragma unroll
  for (int i=0;i<8;++i) orow[lane + 64*i] = v[i] - ls;
}

// ---------- launcher ----------
extern "C" void kernel_launch(void* const* d_in, const int* in_sizes, int n_in,
                              void* d_out, int out_size, void* d_ws, size_t ws_size,
                              hipStream_t stream)
{
  const float* loc  = (const float*)d_in[0];
  const float* tim  = (const float*)d_in[1];
  const float* hloc = (const float*)d_in[2];
  const float* htim = (const float*)d_in[3];
  const int*   uid  = (const int*)d_in[5];
  const float* fc_attn_w  = (const float*)d_in[8];
  const float* fc_attn_b  = (const float*)d_in[9];
  const float* w_ih = (const float*)d_in[10];
  const float* w_hh = (const float*)d_in[11];
  const float* b_ih = (const float*)d_in[12];
  const float* b_hh = (const float*)d_in[13];
  const float* emb_uid    = (const float*)d_in[14];
  const float* fc_final_w = (const float*)d_in[15];
  const float* fc_final_b = (const float*)d_in[16];
  float* out = (float*)d_out;

  char* ws = (char*)d_ws;
  size_t off = 0;
  auto alloc = [&](size_t b){ size_t o = off; off = (off + b + 255) & ~(size_t)255; return o; };
  size_t o_xcat3 = alloc(4096ULL*1728*2);    // also aliased as y (4 MB) after gi GEMM
  size_t o_hist  = alloc(32768ULL*576*2);    // aliased as ctxpart after history GEMM
  size_t o_wAb   = alloc(512ULL*576*2);
  size_t o_wIb3  = alloc(1536ULL*1728*2);
  size_t o_wFb   = alloc(512ULL*1088*2);
  size_t o_H     = alloc(32768ULL*512*2);
  size_t o_Ht    = alloc(32768ULL*512*2);
  size_t o_gi    = alloc(4096ULL*1536*4);
  size_t o_outc  = alloc(2048ULL*1088*2);
  size_t o_hbuf  = alloc(1024*4);
  size_t o_flags = alloc(512*4);
  size_t o_mp    = alloc(16*2048*4);
  size_t o_lp    = alloc(16*2048*4);
  size_t o_mr    = alloc(2048*4);
  size_t o_lr    = alloc(2048*4);
  (void)ws_size; (void)in_sizes; (void)n_in; (void)out_size;

  unsigned short* xcat3   = (unsigned short*)(ws + o_xcat3);
  unsigned short* histcat = (unsigned short*)(ws + o_hist);
  unsigned short* wAb     = (unsigned short*)(ws + o_wAb);
  unsigned short* wIb3    = (unsigned short*)(ws + o_wIb3);
  unsigned short* wFb     = (unsigned short*)(ws + o_wFb);
  unsigned short* Hb      = (unsigned short*)(ws + o_H);
  unsigned short* Htb     = (unsigned short*)(ws + o_Ht);
  float*          gi      = (float*)(ws + o_gi);
  unsigned short* outc    = (unsigned short*)(ws + o_outc);
  float*          hbuf    = (float*)(ws + o_hbuf);
  unsigned*       flags   = (unsigned*)(ws + o_flags);
  float*          mp      = (float*)(ws + o_mp);
  float*          lp      = (float*)(ws + o_lp);
  float*          mr      = (float*)(ws + o_mr);
  float*          lr      = (float*)(ws + o_lr);
  float*          y       = (float*)(ws + o_xcat3);   // alias
  float*          ctxpart = (float*)(ws + o_hist);    // alias

  gru_init<<<1, 1024, 0, stream>>>(hbuf, flags);
  cat_x3<<<4096, 64, 0, stream>>>(loc, tim, xcat3);
  cat_hist<<<32768, 64, 0, stream>>>(hloc, htim, histcat);
  cast_bf16_k<<<(294912+255)/256, 256, 0, stream>>>(fc_attn_w, wAb, 294912);
  cat_w3<<<1536, 64, 0, stream>>>(w_ih, wIb3);
  cast_bf16_k<<<(557056+255)/256, 256, 0, stream>>>(fc_final_w, wFb, 557056);

  // history = tanh(histcat @ fc_attn_w^T + b) -> bf16 H
  gemm_bt<1><<<dim3(512,8), 256, 0, stream>>>(histcat, wAb, fc_attn_b, nullptr, Hb, 32768, 512, 576);
  transpose_k<<<dim3(16,1024), 256, 0, stream>>>(Hb, Htb, 32768, 512);
  // gi = x @ w_ih^T + b_ih (hi/lo split, K=1728) -> fp32
  gemm_bt<0><<<dim3(64,24), 256, 0, stream>>>(xcat3, wIb3, b_ih, gi, nullptr, 4096, 1536, 1728);
  // sequential GRU over 4096 steps; writes q (bf16) into outcat cols 0..511
  gru_scan<<<32, 512, 0, stream>>>(gi, w_hh, b_hh, hbuf, flags, outc);
  // softmax stats
  attn_stats<<<dim3(32,16), 256, 0, stream>>>(outc, Hb, mp, lp);
  stats_combine<<<32, 64, 0, stream>>>(mp, lp, mr, lr);
  // context partials + reduce (writes outcat cols 512..1023)
  attn_ctx<<<dim3(32,8), 256, 0, stream>>>(outc, Hb, Htb, mr, ctxpart);
  ctx_reduce<<<4096, 256, 0, stream>>>(ctxpart, lr, outc);
  // uid embedding (outcat cols 1024..1087)
  uid_gather<<<2048, 64, 0, stream>>>(uid, emb_uid, outc);
  // final linear + log_softmax
  gemm_bt<0><<<dim3(32,8), 256, 0, stream>>>(outc, wFb, fc_final_b, y, nullptr, 2048, 512, 1088);
  log_softmax_k<<<2048, 64, 0, stream>>>(y, out);
}

// Round 3
// 13434.875 us; speedup vs baseline: 3.2812x; 1.8633x over previous
//
#include <hip/hip_runtime.h>

// ---------- types & helpers ----------
using short8  = __attribute__((ext_vector_type(8))) short;
using float4v = __attribute__((ext_vector_type(4))) float;

__device__ __forceinline__ unsigned short f2b(float f){
  unsigned u = __float_as_uint(f);
  u += 0x7FFFu + ((u >> 16) & 1u);
  return (unsigned short)(u >> 16);
}
__device__ __forceinline__ float b2f(unsigned short h){
  return __uint_as_float(((unsigned)h) << 16);
}
__device__ __forceinline__ float sigm(float x){ return 1.f/(1.f + __expf(-x)); }
__device__ __forceinline__ float tanh_f(float x){
  float cx = fminf(fmaxf(x, -15.f), 15.f);
  float e = __expf(2.f*cx);
  return (e - 1.f)/(e + 1.f);
}

#define SENT64 0x7F8000007F800000ULL   // two +inf; h is bounded, can never be inf

// ---------- small prep kernels ----------
// ring: 4097 slots x 256 u64 (512 f32). slot0 = h0 = zeros; rest = sentinel.
__global__ void ring_init(unsigned long long* ring){
  size_t i = (size_t)blockIdx.x*256 + threadIdx.x;
  if (i < 256) ring[i] = 0ull;
  else ring[i] = SENT64;   // grid sized exactly to 4097*256
}

__global__ void cat_hist(const float* __restrict__ a, const float* __restrict__ b,
                         unsigned short* __restrict__ d){
  int r = blockIdx.x;
  const float* ar = a + (size_t)r*512;
  const float* br = b + (size_t)r*64;
  unsigned short* dr = d + (size_t)r*576;
  for (int c = threadIdx.x; c < 576; c += 64){
    float v = (c < 512) ? ar[c] : br[c-512];
    dr[c] = f2b(v);
  }
}

// x concat with hi/lo split: [hi | lo | hi], K=1728
__global__ void cat_x3(const float* __restrict__ a, const float* __restrict__ b,
                       unsigned short* __restrict__ d){
  int r = blockIdx.x;
  const float* ar = a + (size_t)r*512;
  const float* br = b + (size_t)r*64;
  unsigned short* dr = d + (size_t)r*1728;
  for (int c = threadIdx.x; c < 576; c += 64){
    float v = (c < 512) ? ar[c] : br[c-512];
    unsigned short hi = f2b(v);
    unsigned short lo = f2b(v - b2f(hi));
    dr[c] = hi; dr[576+c] = lo; dr[1152+c] = hi;
  }
}

// w_ih split: [hi | hi | lo]  so sum gives x_hi*w_hi + x_lo*w_hi + x_hi*w_lo
__global__ void cat_w3(const float* __restrict__ w, unsigned short* __restrict__ d){
  int r = blockIdx.x;
  const float* wr_ = w + (size_t)r*576;
  unsigned short* dr = d + (size_t)r*1728;
  for (int c = threadIdx.x; c < 576; c += 64){
    float v = wr_[c];
    unsigned short hi = f2b(v);
    unsigned short lo = f2b(v - b2f(hi));
    dr[c] = hi; dr[576+c] = hi; dr[1152+c] = lo;
  }
}

__global__ void cast_bf16_k(const float* __restrict__ s, unsigned short* __restrict__ d, int n){
  int i = blockIdx.x*256 + threadIdx.x;
  if (i < n) d[i] = f2b(s[i]);
}

__global__ void transpose_k(const unsigned short* __restrict__ src,
                            unsigned short* __restrict__ dst, int R, int C){
  __shared__ unsigned short t[32][33];
  int x = threadIdx.x & 31, y = threadIdx.x >> 5;   // 256 threads: 8 rows/pass
  int r0 = blockIdx.y*32, c0 = blockIdx.x*32;
  for (int p=0;p<4;++p) t[y+p*8][x] = src[(size_t)(r0+y+p*8)*C + c0+x];
  __syncthreads();
  for (int p=0;p<4;++p) dst[(size_t)(c0+y+p*8)*R + r0+x] = t[x][y+p*8];
}

__global__ void uid_gather(const int* __restrict__ uid, const float* __restrict__ emb,
                           unsigned short* __restrict__ outcat){
  int r = blockIdx.x, e = threadIdx.x;
  outcat[(size_t)r*1088 + 1024 + e] = f2b(emb[(size_t)uid[r]*64 + e]);
}

// ---------- GEMM: C = A(MxK) * B(NxK)^T (+bias)(+tanh), bf16 in, f32 acc ----------
template<int ACT>
__global__ __launch_bounds__(256) void gemm_bt(
  const unsigned short* __restrict__ A, const unsigned short* __restrict__ B,
  const float* __restrict__ bias, float* __restrict__ Cf, unsigned short* __restrict__ Cb,
  int M, int N, int K)
{
  __shared__ unsigned short As[64*40];
  __shared__ unsigned short Bs[64*40];
  const int tid  = threadIdx.x;
  const int lane = tid & 63, wave = tid >> 6;
  const int wr = (wave>>1)*32, wc = (wave&1)*32;
  const int qa = lane>>4, la = lane&15;
  const int arow = tid>>2, acol = (tid&3)*8;
  const int tiles = K >> 5;
  const size_t abase = (size_t)(blockIdx.x*64 + arow)*K + acol;
  const size_t bbase = (size_t)(blockIdx.y*64 + arow)*K + acol;
  float4v acc[2][2] = {};
  short8 av = *(const short8*)(A + abase);
  short8 bv = *(const short8*)(B + bbase);
  for (int kt=0; kt<tiles; ++kt){
    __syncthreads();
    *(short8*)(As + arow*40 + acol) = av;
    *(short8*)(Bs + arow*40 + acol) = bv;
    __syncthreads();
    if (kt+1 < tiles){
      av = *(const short8*)(A + abase + (size_t)(kt+1)*32);
      bv = *(const short8*)(B + bbase + (size_t)(kt+1)*32);
    }
    short8 af0 = *(const short8*)(As + (wr+la)*40 + qa*8);
    short8 af1 = *(const short8*)(As + (wr+16+la)*40 + qa*8);
    short8 bf0 = *(const short8*)(Bs + (wc+la)*40 + qa*8);
    short8 bf1 = *(const short8*)(Bs + (wc+16+la)*40 + qa*8);
    acc[0][0] = __builtin_amdgcn_mfma_f32_16x16x32_bf16(af0, bf0, acc[0][0],0,0,0);
    acc[0][1] = __builtin_amdgcn_mfma_f32_16x16x32_bf16(af0, bf1, acc[0][1],0,0,0);
    acc[1][0] = __builtin_amdgcn_mfma_f32_16x16x32_bf16(af1, bf0, acc[1][0],0,0,0);
    acc[1][1] = __builtin_amdgcn_mfma_f32_16x16x32_bf16(af1, bf1, acc[1][1],0,0,0);
  }
  for (int mi=0;mi<2;++mi) for (int ni=0;ni<2;++ni){
    int n = blockIdx.y*64 + wc + ni*16 + la;
    float bvv = bias ? bias[n] : 0.f;
    for (int r=0;r<4;++r){
      int m = blockIdx.x*64 + wr + mi*16 + qa*4 + r;
      float v = acc[mi][ni][r] + bvv;
      if (ACT) v = tanh_f(v);
      if (Cf) Cf[(size_t)m*N + n] = v;
      if (Cb) Cb[(size_t)m*N + n] = f2b(v);
    }
  }
}

// ---------- GRU scan: 256 blocks x 64 threads, data-is-the-flag ring ----------
// Wave w (= blockIdx.x) owns h outputs {2w, 2w+1}; publishes them as ONE u64
// relaxed atomic store to ring[t+1][w]. Consumers poll ring words directly
// against the sentinel — no flags, no fences, no __syncthreads.
// Lane covers h columns [8*lane, 8*lane+8); 6 row-partials (3 gates x 2 outs)
// reduce via a 3-level reduce-scatter tree + 3 xor folds.
__global__ __launch_bounds__(64) void gru_scan(
  const float* __restrict__ gi, const float* __restrict__ whh, const float* __restrict__ bhh,
  unsigned long long* ring, unsigned short* __restrict__ outcat)
{
  const int lane = threadIdx.x;
  const int w = blockIdx.x;                   // 0..255
  const int obase = w*2;                      // this wave's 2 outputs
  // weights: wgt[s][m] = w_hh[g*512 + obase + q][lane*8 + m], s = g*2+q
  float wgt[6][8];
  #pragma unroll
  for (int s=0; s<6; ++s){
    int g = s >> 1, q = s & 1;
    const float* wr_ = whh + (size_t)(g*512 + obase + q)*512 + lane*8;
    #pragma unroll
    for (int m=0; m<8; ++m) wgt[s][m] = wr_[m];
  }
  const int myj = obase + lane;               // valid for lane<2
  float br=0.f, bz=0.f, bn=0.f;
  if (lane < 2){ br = bhh[myj]; bz = bhh[512+myj]; bn = bhh[1024+myj]; }
  float hprev = 0.f;                          // lane<2: own h, kept in-register

  auto red = [&](float a, float b, int bit, int d) -> float {
    float kept = bit ? b : a;
    float sent = bit ? a : b;
    float recv = __shfl_xor(sent, d, 64);
    return kept + recv;
  };
  const int bit0 = lane & 1, bit1 = (lane>>1)&1, bit2 = (lane>>2)&1;

  for (int t=0; t<4096; ++t){
    const unsigned long long* rc = ring + (size_t)t*256 + lane*4;
    // prefetch gi (independent of the poll)
    float ir=0.f, iz=0.f, inn=0.f;
    if (lane < 2){
      const float* g = gi + (size_t)t*1536;
      ir = g[myj]; iz = g[512+myj]; inn = g[1024+myj];
    }
    // poll the 4 data words directly (value == readiness)
    unsigned long long a0,a1,a2,a3;
    for(;;){
      a0 = __hip_atomic_load(rc+0, __ATOMIC_RELAXED, __HIP_MEMORY_SCOPE_AGENT);
      a1 = __hip_atomic_load(rc+1, __ATOMIC_RELAXED, __HIP_MEMORY_SCOPE_AGENT);
      a2 = __hip_atomic_load(rc+2, __ATOMIC_RELAXED, __HIP_MEMORY_SCOPE_AGENT);
      a3 = __hip_atomic_load(rc+3, __ATOMIC_RELAXED, __HIP_MEMORY_SCOPE_AGENT);
      bool bad = (a0==SENT64)|(a1==SENT64)|(a2==SENT64)|(a3==SENT64);
      if (!__any(bad)) break;
    }
    float hv[8];
    hv[0]=__uint_as_float((unsigned)a0); hv[1]=__uint_as_float((unsigned)(a0>>32));
    hv[2]=__uint_as_float((unsigned)a1); hv[3]=__uint_as_float((unsigned)(a1>>32));
    hv[4]=__uint_as_float((unsigned)a2); hv[5]=__uint_as_float((unsigned)(a2>>32));
    hv[6]=__uint_as_float((unsigned)a3); hv[7]=__uint_as_float((unsigned)(a3>>32));
    float p0=0,p1=0,p2=0,p3=0,p4=0,p5=0;
    #pragma unroll
    for (int m=0; m<8; ++m){
      float h = hv[m];
      p0 += wgt[0][m]*h; p1 += wgt[1][m]*h; p2 += wgt[2][m]*h;
      p3 += wgt[3][m]*h; p4 += wgt[4][m]*h; p5 += wgt[5][m]*h;
    }
    // reduce-scatter: final v = full sum of slot (lane&7)
    float q0 = red(p0,p1,bit0,1);
    float q1 = red(p2,p3,bit0,1);
    float q2 = red(p4,p5,bit0,1);
    float q3 = 0.f;
    float r0 = red(q0,q1,bit1,2);
    float r1 = red(q2,q3,bit1,2);
    float v  = red(r0,r1,bit2,4);
    v += __shfl_xor(v, 8, 64);
    v += __shfl_xor(v, 16, 64);
    v += __shfl_xor(v, 32, 64);
    // slot layout: 0,1 = r gates; 2,3 = z; 4,5 = n  (for outputs q=0,1)
    float sz = __shfl(v, lane+2, 64);
    float sn = __shfl(v, lane+4, 64);
    float hval = 0.f;
    if (lane < 2){
      float r = sigm(ir + v + br);
      float z = sigm(iz + sz + bz);
      float n = tanh_f(inn + r*(sn + bn));
      hval = (1.f - z)*n + z*hprev;
      hprev = hval;                      // own h stays in-register
    }
    float other = __shfl(hval, 1, 64);   // lane1's value into lane0
    if (lane == 0){
      unsigned long long pack = (unsigned long long)__float_as_uint(hval)
                              | ((unsigned long long)__float_as_uint(other) << 32);
      __hip_atomic_store(ring + (size_t)(t+1)*256 + w, pack,
                         __ATOMIC_RELAXED, __HIP_MEMORY_SCOPE_AGENT);
      if (t >= 2048){
        unsigned opack = (unsigned)f2b(hval) | ((unsigned)f2b(other) << 16);
        *(unsigned*)(outcat + (size_t)(t-2048)*1088 + obase) = opack;
      }
    }
  }
}

// ---------- attention pass 1: per-row max & sumexp (split over 16) ----------
__global__ __launch_bounds__(256) void attn_stats(
  const unsigned short* __restrict__ Q, const unsigned short* __restrict__ H,
  float* __restrict__ mpart, float* __restrict__ lpart)
{
  __shared__ unsigned short qs[64*520];
  const int tid = threadIdx.x;
  const int lane = tid&63, wave = tid>>6;
  const int qa = lane>>4, la = lane&15;
  const int qt = blockIdx.x, sp = blockIdx.y;
  for (int p=0;p<16;++p){
    int idx = p*256 + tid;
    int row = idx>>6, c8 = (idx&63)*8;
    *(short8*)(qs + row*520 + c8) = *(const short8*)(Q + (size_t)(qt*64+row)*1088 + c8);
  }
  __syncthreads();
  const int rowbase = wave*16;
  float mrun[4] = {-3e38f,-3e38f,-3e38f,-3e38f};
  float lrun[4] = {0.f,0.f,0.f,0.f};
  for (int c=0;c<32;++c){
    int hb = sp*2048 + c*64;
    float4v sacc[4] = {};
    for (int ks=0; ks<16; ++ks){
      short8 af = *(const short8*)(qs + (rowbase+la)*520 + ks*32 + qa*8);
      #pragma unroll
      for (int ni=0; ni<4; ++ni){
        short8 bf = *(const short8*)(H + (size_t)(hb + ni*16 + la)*512 + ks*32 + qa*8);
        sacc[ni] = __builtin_amdgcn_mfma_f32_16x16x32_bf16(af, bf, sacc[ni],0,0,0);
      }
    }
    #pragma unroll
    for (int r=0;r<4;++r){
      float cm = fmaxf(fmaxf(sacc[0][r],sacc[1][r]), fmaxf(sacc[2][r],sacc[3][r]));
      cm = fmaxf(cm, __shfl_xor(cm,1,64));
      cm = fmaxf(cm, __shfl_xor(cm,2,64));
      cm = fmaxf(cm, __shfl_xor(cm,4,64));
      cm = fmaxf(cm, __shfl_xor(cm,8,64));
      float mnew = fmaxf(mrun[r], cm);
      float ls = __expf(sacc[0][r]-mnew)+__expf(sacc[1][r]-mnew)
               + __expf(sacc[2][r]-mnew)+__expf(sacc[3][r]-mnew);
      ls += __shfl_xor(ls,1,64); ls += __shfl_xor(ls,2,64);
      ls += __shfl_xor(ls,4,64); ls += __shfl_xor(ls,8,64);
      lrun[r] = lrun[r]*__expf(mrun[r]-mnew) + ls;
      mrun[r] = mnew;
    }
  }
  if (la == 0){
    #pragma unroll
    for (int r=0;r<4;++r){
      int row = qt*64 + rowbase + qa*4 + r;
      mpart[sp*2048 + row] = mrun[r];
      lpart[sp*2048 + row] = lrun[r];
    }
  }
}

__global__ void stats_combine(const float* __restrict__ mpart, const float* __restrict__ lpart,
                              float* __restrict__ mrow, float* __restrict__ lrow){
  int r = blockIdx.x*64 + threadIdx.x;
  float m = -3e38f;
  for (int s=0;s<16;++s) m = fmaxf(m, mpart[s*2048 + r]);
  float l = 0.f;
  for (int s=0;s<16;++s) l += lpart[s*2048 + r]*__expf(mpart[s*2048 + r] - m);
  mrow[r] = m; lrow[r] = l;
}

// ---------- attention pass 2: context partials (split over 8) ----------
__global__ __launch_bounds__(256) void attn_ctx(
  const unsigned short* __restrict__ Q, const unsigned short* __restrict__ H,
  const unsigned short* __restrict__ Ht, const float* __restrict__ mrow,
  float* __restrict__ ctxpart)
{
  __shared__ unsigned short qs[64*520];
  __shared__ unsigned short ps[4*16*80];
  const int tid = threadIdx.x;
  const int lane = tid&63, wave = tid>>6;
  const int qa = lane>>4, la = lane&15;
  const int qt = blockIdx.x, sp = blockIdx.y;
  for (int p=0;p<16;++p){
    int idx = p*256 + tid;
    int row = idx>>6, c8 = (idx&63)*8;
    *(short8*)(qs + row*520 + c8) = *(const short8*)(Q + (size_t)(qt*64+row)*1088 + c8);
  }
  __syncthreads();
  const int rowbase = wave*16;
  float mreg[4];
  #pragma unroll
  for (int r=0;r<4;++r) mreg[r] = mrow[qt*64 + rowbase + qa*4 + r];
  float4v cacc[32] = {};
  unsigned short* pw = ps + wave*16*80;
  for (int c=0;c<64;++c){
    int hb = sp*4096 + c*64;
    float4v sacc[4] = {};
    for (int ks=0; ks<16; ++ks){
      short8 af = *(const short8*)(qs + (rowbase+la)*520 + ks*32 + qa*8);
      #pragma unroll
      for (int ni=0; ni<4; ++ni){
        short8 bf = *(const short8*)(H + (size_t)(hb + ni*16 + la)*512 + ks*32 + qa*8);
        sacc[ni] = __builtin_amdgcn_mfma_f32_16x16x32_bf16(af, bf, sacc[ni],0,0,0);
      }
    }
    #pragma unroll
    for (int ni=0;ni<4;++ni)
      #pragma unroll
      for (int r=0;r<4;++r)
        pw[(qa*4+r)*80 + ni*16 + la] = f2b(__expf(sacc[ni][r]-mreg[r]));
    #pragma unroll
    for (int ks2=0; ks2<2; ++ks2){
      short8 paf = *(const short8*)(pw + la*80 + ks2*32 + qa*8);
      for (int f=0; f<32; ++f){
        short8 bf = *(const short8*)(Ht + (size_t)(f*16+la)*32768 + hb + ks2*32 + qa*8);
        cacc[f] = __builtin_amdgcn_mfma_f32_16x16x32_bf16(paf, bf, cacc[f],0,0,0);
      }
    }
  }
  for (int f=0; f<32; ++f)
    #pragma unroll
    for (int r=0;r<4;++r){
      int row = qt*64 + rowbase + qa*4 + r;
      ctxpart[((size_t)sp*2048 + row)*512 + f*16 + la] = cacc[f][r];
    }
}

__global__ void ctx_reduce(const float* __restrict__ ctxpart, const float* __restrict__ lrow,
                           unsigned short* __restrict__ outcat){
  int idx = blockIdx.x*256 + threadIdx.x;
  int r = idx >> 9, cc = idx & 511;
  float s = 0.f;
  for (int sp=0; sp<8; ++sp) s += ctxpart[((size_t)sp*2048 + r)*512 + cc];
  outcat[(size_t)r*1088 + 512 + cc] = f2b(s / lrow[r]);
}

__global__ void log_softmax_k(const float* __restrict__ y, float* __restrict__ out){
  int r = blockIdx.x, lane = threadIdx.x;
  const float* yr = y + (size_t)r*512;
  float v[8]; float m = -3e38f;
  #pragma unroll
  for (int i=0;i<8;++i){ v[i] = yr[lane + 64*i]; m = fmaxf(m, v[i]); }
  #pragma unroll
  for (int d=1; d<64; d<<=1) m = fmaxf(m, __shfl_xor(m,d,64));
  float s = 0.f;
  #pragma unroll
  for (int i=0;i<8;++i) s += __expf(v[i]-m);
  #pragma unroll
  for (int d=1; d<64; d<<=1) s += __shfl_xor(s,d,64);
  float ls = __logf(s) + m;
  float* orow = out + (size_t)r*512;
  #pragma unroll
  for (int i=0;i<8;++i) orow[lane + 64*i] = v[i] - ls;
}

// ---------- launcher ----------
extern "C" void kernel_launch(void* const* d_in, const int* in_sizes, int n_in,
                              void* d_out, int out_size, void* d_ws, size_t ws_size,
                              hipStream_t stream)
{
  const float* loc  = (const float*)d_in[0];
  const float* tim  = (const float*)d_in[1];
  const float* hloc = (const float*)d_in[2];
  const float* htim = (const float*)d_in[3];
  const int*   uid  = (const int*)d_in[5];
  const float* fc_attn_w  = (const float*)d_in[8];
  const float* fc_attn_b  = (const float*)d_in[9];
  const float* w_ih = (const float*)d_in[10];
  const float* w_hh = (const float*)d_in[11];
  const float* b_ih = (const float*)d_in[12];
  const float* b_hh = (const float*)d_in[13];
  const float* emb_uid    = (const float*)d_in[14];
  const float* fc_final_w = (const float*)d_in[15];
  const float* fc_final_b = (const float*)d_in[16];
  float* out = (float*)d_out;

  char* ws = (char*)d_ws;
  size_t off = 0;
  auto alloc = [&](size_t b){ size_t o = off; off = (off + b + 255) & ~(size_t)255; return o; };
  size_t o_xcat3 = alloc(4096ULL*1728*2);    // also aliased as y (4 MB) after gi GEMM
  size_t o_hist  = alloc(32768ULL*576*2);    // aliased as ctxpart after history GEMM
  size_t o_wAb   = alloc(512ULL*576*2);
  size_t o_wIb3  = alloc(1536ULL*1728*2);
  size_t o_wFb   = alloc(512ULL*1088*2);
  size_t o_H     = alloc(32768ULL*512*2);
  size_t o_Ht    = alloc(32768ULL*512*2);
  size_t o_gi    = alloc(4096ULL*1536*4);
  size_t o_outc  = alloc(2048ULL*1088*2);
  size_t o_ring  = alloc(4097ULL*256*8);     // h ring: 4097 slots x 512 f32
  size_t o_mp    = alloc(16*2048*4);
  size_t o_lp    = alloc(16*2048*4);
  size_t o_mr    = alloc(2048*4);
  size_t o_lr    = alloc(2048*4);
  (void)ws_size; (void)in_sizes; (void)n_in; (void)out_size;

  unsigned short* xcat3   = (unsigned short*)(ws + o_xcat3);
  unsigned short* histcat = (unsigned short*)(ws + o_hist);
  unsigned short* wAb     = (unsigned short*)(ws + o_wAb);
  unsigned short* wIb3    = (unsigned short*)(ws + o_wIb3);
  unsigned short* wFb     = (unsigned short*)(ws + o_wFb);
  unsigned short* Hb      = (unsigned short*)(ws + o_H);
  unsigned short* Htb     = (unsigned short*)(ws + o_Ht);
  float*          gi      = (float*)(ws + o_gi);
  unsigned short* outc    = (unsigned short*)(ws + o_outc);
  unsigned long long* ring = (unsigned long long*)(ws + o_ring);
  float*          mp      = (float*)(ws + o_mp);
  float*          lp      = (float*)(ws + o_lp);
  float*          mr      = (float*)(ws + o_mr);
  float*          lr      = (float*)(ws + o_lr);
  float*          y       = (float*)(ws + o_xcat3);   // alias
  float*          ctxpart = (float*)(ws + o_hist);    // alias

  ring_init<<<4097, 256, 0, stream>>>(ring);
  cat_x3<<<4096, 64, 0, stream>>>(loc, tim, xcat3);
  cat_hist<<<32768, 64, 0, stream>>>(hloc, htim, histcat);
  cast_bf16_k<<<(294912+255)/256, 256, 0, stream>>>(fc_attn_w, wAb, 294912);
  cat_w3<<<1536, 64, 0, stream>>>(w_ih, wIb3);
  cast_bf16_k<<<(557056+255)/256, 256, 0, stream>>>(fc_final_w, wFb, 557056);

  // history = tanh(histcat @ fc_attn_w^T + b) -> bf16 H
  gemm_bt<1><<<dim3(512,8), 256, 0, stream>>>(histcat, wAb, fc_attn_b, nullptr, Hb, 32768, 512, 576);
  transpose_k<<<dim3(16,1024), 256, 0, stream>>>(Hb, Htb, 32768, 512);
  // gi = x @ w_ih^T + b_ih (hi/lo split, K=1728) -> fp32
  gemm_bt<0><<<dim3(64,24), 256, 0, stream>>>(xcat3, wIb3, b_ih, gi, nullptr, 4096, 1536, 1728);
  // sequential GRU over 4096 steps; writes q (bf16) into outcat cols 0..511
  gru_scan<<<256, 64, 0, stream>>>(gi, w_hh, b_hh, ring, outc);
  // softmax stats
  attn_stats<<<dim3(32,16), 256, 0, stream>>>(outc, Hb, mp, lp);
  stats_combine<<<32, 64, 0, stream>>>(mp, lp, mr, lr);
  // context partials + reduce (writes outcat cols 512..1023)
  attn_ctx<<<dim3(32,8), 256, 0, stream>>>(outc, Hb, Htb, mr, ctxpart);
  ctx_reduce<<<4096, 256, 0, stream>>>(ctxpart, lr, outc);
  // uid embedding (outcat cols 1024..1087)
  uid_gather<<<2048, 64, 0, stream>>>(uid, emb_uid, outc);
  // final linear + log_softmax
  gemm_bt<0><<<dim3(32,8), 256, 0, stream>>>(outc, wFb, fc_final_b, y, nullptr, 2048, 512, 1088);
  log_softmax_k<<<2048, 64, 0, stream>>>(y, out);
}

// Round 4
// 10472.849 us; speedup vs baseline: 4.2092x; 1.2828x over previous
//
#include <hip/hip_runtime.h>

// ---------- types & helpers ----------
using short8  = __attribute__((ext_vector_type(8))) short;
using float4v = __attribute__((ext_vector_type(4))) float;

__device__ __forceinline__ unsigned short f2b(float f){
  unsigned u = __float_as_uint(f);
  u += 0x7FFFu + ((u >> 16) & 1u);
  return (unsigned short)(u >> 16);
}
__device__ __forceinline__ float b2f(unsigned short h){
  return __uint_as_float(((unsigned)h) << 16);
}
__device__ __forceinline__ float sigm(float x){ return 1.f/(1.f + __expf(-x)); }
__device__ __forceinline__ float tanh_f(float x){
  float cx = fminf(fmaxf(x, -15.f), 15.f);
  float e = __expf(2.f*cx);
  return (e - 1.f)/(e + 1.f);
}

#define SENT64 0x7F8000007F800000ULL   // two +inf; h is bounded, can never be inf

// ---------- small prep kernels ----------
// ring: 4097 slots x 512 u64 (4 KB; producer b owns the 64B line at b*64).
// slot0 = h0 = zeros; rest = sentinel.  grid must cover 4097*512 exactly.
__global__ void ring_init(unsigned long long* ring){
  size_t i = (size_t)blockIdx.x*256 + threadIdx.x;
  if (i < 512) ring[i] = 0ull;
  else ring[i] = SENT64;
}

__global__ void cat_hist(const float* __restrict__ a, const float* __restrict__ b,
                         unsigned short* __restrict__ d){
  int r = blockIdx.x;
  const float* ar = a + (size_t)r*512;
  const float* br = b + (size_t)r*64;
  unsigned short* dr = d + (size_t)r*576;
  for (int c = threadIdx.x; c < 576; c += 64){
    float v = (c < 512) ? ar[c] : br[c-512];
    dr[c] = f2b(v);
  }
}

// x concat with hi/lo split: [hi | lo | hi], K=1728
__global__ void cat_x3(const float* __restrict__ a, const float* __restrict__ b,
                       unsigned short* __restrict__ d){
  int r = blockIdx.x;
  const float* ar = a + (size_t)r*512;
  const float* br = b + (size_t)r*64;
  unsigned short* dr = d + (size_t)r*1728;
  for (int c = threadIdx.x; c < 576; c += 64){
    float v = (c < 512) ? ar[c] : br[c-512];
    unsigned short hi = f2b(v);
    unsigned short lo = f2b(v - b2f(hi));
    dr[c] = hi; dr[576+c] = lo; dr[1152+c] = hi;
  }
}

// w_ih split: [hi | hi | lo]  so sum gives x_hi*w_hi + x_lo*w_hi + x_hi*w_lo
__global__ void cat_w3(const float* __restrict__ w, unsigned short* __restrict__ d){
  int r = blockIdx.x;
  const float* wr_ = w + (size_t)r*576;
  unsigned short* dr = d + (size_t)r*1728;
  for (int c = threadIdx.x; c < 576; c += 64){
    float v = wr_[c];
    unsigned short hi = f2b(v);
    unsigned short lo = f2b(v - b2f(hi));
    dr[c] = hi; dr[576+c] = hi; dr[1152+c] = lo;
  }
}

__global__ void cast_bf16_k(const float* __restrict__ s, unsigned short* __restrict__ d, int n){
  int i = blockIdx.x*256 + threadIdx.x;
  if (i < n) d[i] = f2b(s[i]);
}

__global__ void transpose_k(const unsigned short* __restrict__ src,
                            unsigned short* __restrict__ dst, int R, int C){
  __shared__ unsigned short t[32][33];
  int x = threadIdx.x & 31, y = threadIdx.x >> 5;   // 256 threads: 8 rows/pass
  int r0 = blockIdx.y*32, c0 = blockIdx.x*32;
  for (int p=0;p<4;++p) t[y+p*8][x] = src[(size_t)(r0+y+p*8)*C + c0+x];
  __syncthreads();
  for (int p=0;p<4;++p) dst[(size_t)(c0+y+p*8)*R + r0+x] = t[x][y+p*8];
}

__global__ void uid_gather(const int* __restrict__ uid, const float* __restrict__ emb,
                           unsigned short* __restrict__ outcat){
  int r = blockIdx.x, e = threadIdx.x;
  outcat[(size_t)r*1088 + 1024 + e] = f2b(emb[(size_t)uid[r]*64 + e]);
}

// ---------- GEMM: C = A(MxK) * B(NxK)^T (+bias)(+tanh), bf16 in, f32 acc ----------
template<int ACT>
__global__ __launch_bounds__(256) void gemm_bt(
  const unsigned short* __restrict__ A, const unsigned short* __restrict__ B,
  const float* __restrict__ bias, float* __restrict__ Cf, unsigned short* __restrict__ Cb,
  int M, int N, int K)
{
  __shared__ unsigned short As[64*40];
  __shared__ unsigned short Bs[64*40];
  const int tid  = threadIdx.x;
  const int lane = tid & 63, wave = tid >> 6;
  const int wr = (wave>>1)*32, wc = (wave&1)*32;
  const int qa = lane>>4, la = lane&15;
  const int arow = tid>>2, acol = (tid&3)*8;
  const int tiles = K >> 5;
  const size_t abase = (size_t)(blockIdx.x*64 + arow)*K + acol;
  const size_t bbase = (size_t)(blockIdx.y*64 + arow)*K + acol;
  float4v acc[2][2] = {};
  short8 av = *(const short8*)(A + abase);
  short8 bv = *(const short8*)(B + bbase);
  for (int kt=0; kt<tiles; ++kt){
    __syncthreads();
    *(short8*)(As + arow*40 + acol) = av;
    *(short8*)(Bs + arow*40 + acol) = bv;
    __syncthreads();
    if (kt+1 < tiles){
      av = *(const short8*)(A + abase + (size_t)(kt+1)*32);
      bv = *(const short8*)(B + bbase + (size_t)(kt+1)*32);
    }
    short8 af0 = *(const short8*)(As + (wr+la)*40 + qa*8);
    short8 af1 = *(const short8*)(As + (wr+16+la)*40 + qa*8);
    short8 bf0 = *(const short8*)(Bs + (wc+la)*40 + qa*8);
    short8 bf1 = *(const short8*)(Bs + (wc+16+la)*40 + qa*8);
    acc[0][0] = __builtin_amdgcn_mfma_f32_16x16x32_bf16(af0, bf0, acc[0][0],0,0,0);
    acc[0][1] = __builtin_amdgcn_mfma_f32_16x16x32_bf16(af0, bf1, acc[0][1],0,0,0);
    acc[1][0] = __builtin_amdgcn_mfma_f32_16x16x32_bf16(af1, bf0, acc[1][0],0,0,0);
    acc[1][1] = __builtin_amdgcn_mfma_f32_16x16x32_bf16(af1, bf1, acc[1][1],0,0,0);
  }
  for (int mi=0;mi<2;++mi) for (int ni=0;ni<2;++ni){
    int n = blockIdx.y*64 + wc + ni*16 + la;
    float bvv = bias ? bias[n] : 0.f;
    for (int r=0;r<4;++r){
      int m = blockIdx.x*64 + wr + mi*16 + qa*4 + r;
      float v = acc[mi][ni][r] + bvv;
      if (ACT) v = tanh_f(v);
      if (Cf) Cf[(size_t)m*N + n] = v;
      if (Cb) Cb[(size_t)m*N + n] = f2b(v);
    }
  }
}

// ---------- GRU scan: 64 blocks x 64 threads, single-writer-line ring ----------
// Block b owns h outputs [8b, 8b+8). It publishes them into ONE 64-byte line
// (4 u64) of ring slot t+1 — each line has exactly one writer, so it is
// invalidated exactly once per step. Consumer lane L reads producer L's line,
// which is exactly the 8 h columns lane L needs for its weight chunk.
// 24 gate rows (3 gates x 8 outputs) x 8 cols/lane, reduce-scatter over 32
// slots leaves row s's full sum in lane s (s<24).
__global__ __launch_bounds__(64,1) void gru_scan(
  const float* __restrict__ gi, const float* __restrict__ whh, const float* __restrict__ bhh,
  unsigned long long* ring, unsigned short* __restrict__ outcat)
{
  const int lane = threadIdx.x;               // 0..63
  const int b = blockIdx.x;                   // 0..63
  const int ob = b*8;                         // first owned output
  // wgt[s][m] = w_hh[(s>>3)*512 + ob + (s&7)][lane*8 + m]
  float wgt[24][8];
  #pragma unroll
  for (int s=0; s<24; ++s){
    const float* wr_ = whh + (size_t)((s>>3)*512 + ob + (s&7))*512 + lane*8;
    #pragma unroll
    for (int m=0; m<8; ++m) wgt[s][m] = wr_[m];
  }
  // per-slot bias (lanes 0..23): slot l -> gate l>>3, output ob+(l&7)
  float bh = 0.f;
  if (lane < 24) bh = bhh[(lane>>3)*512 + ob + (lane&7)];
  float hprev = 0.f;                          // lanes 0..7: own h value

  const int bit0=lane&1, bit1=(lane>>1)&1, bit2=(lane>>2)&1,
            bit3=(lane>>3)&1, bit4=(lane>>4)&1;

  for (int t=0; t<4096; ++t){
    // prefetch gi slot value (lanes 0..23), independent of the poll
    float gval = 0.f;
    if (lane < 24) gval = gi[(size_t)t*1536 + (lane>>3)*512 + ob + (lane&7)];
    // poll own producer line: lane L <- producer L's 4 u64 = h[8L..8L+8)
    const unsigned long long* rc = ring + (size_t)t*512 + lane*8;
    unsigned long long a0,a1,a2,a3;
    for(;;){
      a0 = __hip_atomic_load(rc+0, __ATOMIC_RELAXED, __HIP_MEMORY_SCOPE_AGENT);
      a1 = __hip_atomic_load(rc+1, __ATOMIC_RELAXED, __HIP_MEMORY_SCOPE_AGENT);
      a2 = __hip_atomic_load(rc+2, __ATOMIC_RELAXED, __HIP_MEMORY_SCOPE_AGENT);
      a3 = __hip_atomic_load(rc+3, __ATOMIC_RELAXED, __HIP_MEMORY_SCOPE_AGENT);
      bool bad = (a0==SENT64)|(a1==SENT64)|(a2==SENT64)|(a3==SENT64);
      if (!__any(bad)) break;
    }
    float hv[8];
    hv[0]=__uint_as_float((unsigned)a0); hv[1]=__uint_as_float((unsigned)(a0>>32));
    hv[2]=__uint_as_float((unsigned)a1); hv[3]=__uint_as_float((unsigned)(a1>>32));
    hv[4]=__uint_as_float((unsigned)a2); hv[5]=__uint_as_float((unsigned)(a2>>32));
    hv[6]=__uint_as_float((unsigned)a3); hv[7]=__uint_as_float((unsigned)(a3>>32));
    // 24 row-partials over this lane's 8 columns
    float v[32];
    #pragma unroll
    for (int s=0; s<24; ++s){
      float acc = 0.f;
      #pragma unroll
      for (int m=0; m<8; ++m) acc += wgt[s][m]*hv[m];
      v[s] = acc;
    }
    #pragma unroll
    for (int s=24; s<32; ++s) v[s] = 0.f;
    // reduce-scatter over 32 slots: lane l ends with full sum of slot (l&31)
    float s16[16];
    #pragma unroll
    for (int j=0; j<16; ++j){
      float keep = bit0 ? v[2*j+1] : v[2*j];
      float send = bit0 ? v[2*j]   : v[2*j+1];
      s16[j] = keep + __shfl_xor(send, 1, 64);
    }
    float s8[8];
    #pragma unroll
    for (int j=0; j<8; ++j){
      float keep = bit1 ? s16[2*j+1] : s16[2*j];
      float send = bit1 ? s16[2*j]   : s16[2*j+1];
      s8[j] = keep + __shfl_xor(send, 2, 64);
    }
    float s4[4];
    #pragma unroll
    for (int j=0; j<4; ++j){
      float keep = bit2 ? s8[2*j+1] : s8[2*j];
      float send = bit2 ? s8[2*j]   : s8[2*j+1];
      s4[j] = keep + __shfl_xor(send, 4, 64);
    }
    float s2[2];
    #pragma unroll
    for (int j=0; j<2; ++j){
      float keep = bit3 ? s4[2*j+1] : s4[2*j];
      float send = bit3 ? s4[2*j]   : s4[2*j+1];
      s2[j] = keep + __shfl_xor(send, 8, 64);
    }
    {
      float keep = bit4 ? s2[1] : s2[0];
      float send = bit4 ? s2[0] : s2[1];
      s2[0] = keep + __shfl_xor(send, 16, 64);
    }
    float vsum = s2[0] + __shfl_xor(s2[0], 32, 64);
    // lanes 0..23: slot sum + b_hh; r,z slots also add gi part
    float wsum = vsum + bh;
    float wrz  = wsum + gval;                 // complete pre-act for r,z slots
    float uz  = __shfl(wrz,  lane+8,  64);    // z pre-act -> lanes 0..7
    float hn  = __shfl(wsum, lane+16, 64);    // h_n part (incl b_hn) -> lanes 0..7
    float in_ = __shfl(gval, lane+16, 64);    // i_n -> lanes 0..7
    float hval = 0.f;
    if (lane < 8){
      float r = sigm(wrz);
      float z = sigm(uz);
      float n = tanh_f(in_ + r*hn);
      hval = (1.f - z)*n + z*hprev;
      hprev = hval;
    }
    float nb = __shfl_xor(hval, 1, 64);       // partner h value
    if (lane < 8 && !(lane & 1)){
      unsigned long long pack = (unsigned long long)__float_as_uint(hval)
                              | ((unsigned long long)__float_as_uint(nb) << 32);
      __hip_atomic_store(ring + (size_t)(t+1)*512 + b*8 + (lane>>1), pack,
                         __ATOMIC_RELAXED, __HIP_MEMORY_SCOPE_AGENT);
      if (t >= 2048){
        unsigned opack = (unsigned)f2b(hval) | ((unsigned)f2b(nb) << 16);
        *(unsigned*)(outcat + (size_t)(t-2048)*1088 + ob + lane) = opack;
      }
    }
  }
}

// ---------- attention pass 1: per-row max & sumexp (split over 16) ----------
__global__ __launch_bounds__(256) void attn_stats(
  const unsigned short* __restrict__ Q, const unsigned short* __restrict__ H,
  float* __restrict__ mpart, float* __restrict__ lpart)
{
  __shared__ unsigned short qs[64*520];
  const int tid = threadIdx.x;
  const int lane = tid&63, wave = tid>>6;
  const int qa = lane>>4, la = lane&15;
  const int qt = blockIdx.x, sp = blockIdx.y;
  for (int p=0;p<16;++p){
    int idx = p*256 + tid;
    int row = idx>>6, c8 = (idx&63)*8;
    *(short8*)(qs + row*520 + c8) = *(const short8*)(Q + (size_t)(qt*64+row)*1088 + c8);
  }
  __syncthreads();
  const int rowbase = wave*16;
  float mrun[4] = {-3e38f,-3e38f,-3e38f,-3e38f};
  float lrun[4] = {0.f,0.f,0.f,0.f};
  for (int c=0;c<32;++c){
    int hb = sp*2048 + c*64;
    float4v sacc[4] = {};
    for (int ks=0; ks<16; ++ks){
      short8 af = *(const short8*)(qs + (rowbase+la)*520 + ks*32 + qa*8);
      #pragma unroll
      for (int ni=0; ni<4; ++ni){
        short8 bf = *(const short8*)(H + (size_t)(hb + ni*16 + la)*512 + ks*32 + qa*8);
        sacc[ni] = __builtin_amdgcn_mfma_f32_16x16x32_bf16(af, bf, sacc[ni],0,0,0);
      }
    }
    #pragma unroll
    for (int r=0;r<4;++r){
      float cm = fmaxf(fmaxf(sacc[0][r],sacc[1][r]), fmaxf(sacc[2][r],sacc[3][r]));
      cm = fmaxf(cm, __shfl_xor(cm,1,64));
      cm = fmaxf(cm, __shfl_xor(cm,2,64));
      cm = fmaxf(cm, __shfl_xor(cm,4,64));
      cm = fmaxf(cm, __shfl_xor(cm,8,64));
      float mnew = fmaxf(mrun[r], cm);
      float ls = __expf(sacc[0][r]-mnew)+__expf(sacc[1][r]-mnew)
               + __expf(sacc[2][r]-mnew)+__expf(sacc[3][r]-mnew);
      ls += __shfl_xor(ls,1,64); ls += __shfl_xor(ls,2,64);
      ls += __shfl_xor(ls,4,64); ls += __shfl_xor(ls,8,64);
      lrun[r] = lrun[r]*__expf(mrun[r]-mnew) + ls;
      mrun[r] = mnew;
    }
  }
  if (la == 0){
    #pragma unroll
    for (int r=0;r<4;++r){
      int row = qt*64 + rowbase + qa*4 + r;
      mpart[sp*2048 + row] = mrun[r];
      lpart[sp*2048 + row] = lrun[r];
    }
  }
}

__global__ void stats_combine(const float* __restrict__ mpart, const float* __restrict__ lpart,
                              float* __restrict__ mrow, float* __restrict__ lrow){
  int r = blockIdx.x*64 + threadIdx.x;
  float m = -3e38f;
  for (int s=0;s<16;++s) m = fmaxf(m, mpart[s*2048 + r]);
  float l = 0.f;
  for (int s=0;s<16;++s) l += lpart[s*2048 + r]*__expf(mpart[s*2048 + r] - m);
  mrow[r] = m; lrow[r] = l;
}

// ---------- attention pass 2: context partials (split over 8) ----------
__global__ __launch_bounds__(256) void attn_ctx(
  const unsigned short* __restrict__ Q, const unsigned short* __restrict__ H,
  const unsigned short* __restrict__ Ht, const float* __restrict__ mrow,
  float* __restrict__ ctxpart)
{
  __shared__ unsigned short qs[64*520];
  __shared__ unsigned short ps[4*16*80];
  const int tid = threadIdx.x;
  const int lane = tid&63, wave = tid>>6;
  const int qa = lane>>4, la = lane&15;
  const int qt = blockIdx.x, sp = blockIdx.y;
  for (int p=0;p<16;++p){
    int idx = p*256 + tid;
    int row = idx>>6, c8 = (idx&63)*8;
    *(short8*)(qs + row*520 + c8) = *(const short8*)(Q + (size_t)(qt*64+row)*1088 + c8);
  }
  __syncthreads();
  const int rowbase = wave*16;
  float mreg[4];
  #pragma unroll
  for (int r=0;r<4;++r) mreg[r] = mrow[qt*64 + rowbase + qa*4 + r];
  float4v cacc[32] = {};
  unsigned short* pw = ps + wave*16*80;
  for (int c=0;c<64;++c){
    int hb = sp*4096 + c*64;
    float4v sacc[4] = {};
    for (int ks=0; ks<16; ++ks){
      short8 af = *(const short8*)(qs + (rowbase+la)*520 + ks*32 + qa*8);
      #pragma unroll
      for (int ni=0; ni<4; ++ni){
        short8 bf = *(const short8*)(H + (size_t)(hb + ni*16 + la)*512 + ks*32 + qa*8);
        sacc[ni] = __builtin_amdgcn_mfma_f32_16x16x32_bf16(af, bf, sacc[ni],0,0,0);
      }
    }
    #pragma unroll
    for (int ni=0;ni<4;++ni)
      #pragma unroll
      for (int r=0;r<4;++r)
        pw[(qa*4+r)*80 + ni*16 + la] = f2b(__expf(sacc[ni][r]-mreg[r]));
    #pragma unroll
    for (int ks2=0; ks2<2; ++ks2){
      short8 paf = *(const short8*)(pw + la*80 + ks2*32 + qa*8);
      for (int f=0; f<32; ++f){
        short8 bf = *(const short8*)(Ht + (size_t)(f*16+la)*32768 + hb + ks2*32 + qa*8);
        cacc[f] = __builtin_amdgcn_mfma_f32_16x16x32_bf16(paf, bf, cacc[f],0,0,0);
      }
    }
  }
  for (int f=0; f<32; ++f)
    #pragma unroll
    for (int r=0;r<4;++r){
      int row = qt*64 + rowbase + qa*4 + r;
      ctxpart[((size_t)sp*2048 + row)*512 + f*16 + la] = cacc[f][r];
    }
}

__global__ void ctx_reduce(const float* __restrict__ ctxpart, const float* __restrict__ lrow,
                           unsigned short* __restrict__ outcat){
  int idx = blockIdx.x*256 + threadIdx.x;
  int r = idx >> 9, cc = idx & 511;
  float s = 0.f;
  for (int sp=0; sp<8; ++sp) s += ctxpart[((size_t)sp*2048 + r)*512 + cc];
  outcat[(size_t)r*1088 + 512 + cc] = f2b(s / lrow[r]);
}

__global__ void log_softmax_k(const float* __restrict__ y, float* __restrict__ out){
  int r = blockIdx.x, lane = threadIdx.x;
  const float* yr = y + (size_t)r*512;
  float v[8]; float m = -3e38f;
  #pragma unroll
  for (int i=0;i<8;++i){ v[i] = yr[lane + 64*i]; m = fmaxf(m, v[i]); }
  #pragma unroll
  for (int d=1; d<64; d<<=1) m = fmaxf(m, __shfl_xor(m,d,64));
  float s = 0.f;
  #pragma unroll
  for (int i=0;i<8;++i) s += __expf(v[i]-m);
  #pragma unroll
  for (int d=1; d<64; d<<=1) s += __shfl_xor(s,d,64);
  float ls = __logf(s) + m;
  float* orow = out + (size_t)r*512;
  #pragma unroll
  for (int i=0;i<8;++i) orow[lane + 64*i] = v[i] - ls;
}

// ---------- launcher ----------
extern "C" void kernel_launch(void* const* d_in, const int* in_sizes, int n_in,
                              void* d_out, int out_size, void* d_ws, size_t ws_size,
                              hipStream_t stream)
{
  const float* loc  = (const float*)d_in[0];
  const float* tim  = (const float*)d_in[1];
  const float* hloc = (const float*)d_in[2];
  const float* htim = (const float*)d_in[3];
  const int*   uid  = (const int*)d_in[5];
  const float* fc_attn_w  = (const float*)d_in[8];
  const float* fc_attn_b  = (const float*)d_in[9];
  const float* w_ih = (const float*)d_in[10];
  const float* w_hh = (const float*)d_in[11];
  const float* b_ih = (const float*)d_in[12];
  const float* b_hh = (const float*)d_in[13];
  const float* emb_uid    = (const float*)d_in[14];
  const float* fc_final_w = (const float*)d_in[15];
  const float* fc_final_b = (const float*)d_in[16];
  float* out = (float*)d_out;

  char* ws = (char*)d_ws;
  size_t off = 0;
  auto alloc = [&](size_t b){ size_t o = off; off = (off + b + 255) & ~(size_t)255; return o; };
  size_t o_xcat3 = alloc(4096ULL*1728*2);    // also aliased as y (4 MB) after gi GEMM
  size_t o_hist  = alloc(32768ULL*576*2);    // aliased as ctxpart after history GEMM
  size_t o_wAb   = alloc(512ULL*576*2);
  size_t o_wIb3  = alloc(1536ULL*1728*2);
  size_t o_wFb   = alloc(512ULL*1088*2);
  size_t o_H     = alloc(32768ULL*512*2);
  size_t o_Ht    = alloc(32768ULL*512*2);
  size_t o_gi    = alloc(4096ULL*1536*4);
  size_t o_outc  = alloc(2048ULL*1088*2);
  size_t o_ring  = alloc(4097ULL*512*8);     // h ring: 4097 slots x 4 KB
  size_t o_mp    = alloc(16*2048*4);
  size_t o_lp    = alloc(16*2048*4);
  size_t o_mr    = alloc(2048*4);
  size_t o_lr    = alloc(2048*4);
  (void)ws_size; (void)in_sizes; (void)n_in; (void)out_size;

  unsigned short* xcat3   = (unsigned short*)(ws + o_xcat3);
  unsigned short* histcat = (unsigned short*)(ws + o_hist);
  unsigned short* wAb     = (unsigned short*)(ws + o_wAb);
  unsigned short* wIb3    = (unsigned short*)(ws + o_wIb3);
  unsigned short* wFb     = (unsigned short*)(ws + o_wFb);
  unsigned short* Hb      = (unsigned short*)(ws + o_H);
  unsigned short* Htb     = (unsigned short*)(ws + o_Ht);
  float*          gi      = (float*)(ws + o_gi);
  unsigned short* outc    = (unsigned short*)(ws + o_outc);
  unsigned long long* ring = (unsigned long long*)(ws + o_ring);
  float*          mp      = (float*)(ws + o_mp);
  float*          lp      = (float*)(ws + o_lp);
  float*          mr      = (float*)(ws + o_mr);
  float*          lr      = (float*)(ws + o_lr);
  float*          y       = (float*)(ws + o_xcat3);   // alias
  float*          ctxpart = (float*)(ws + o_hist);    // alias

  ring_init<<<8194, 256, 0, stream>>>(ring);           // 8194*256 == 4097*512
  cat_x3<<<4096, 64, 0, stream>>>(loc, tim, xcat3);
  cat_hist<<<32768, 64, 0, stream>>>(hloc, htim, histcat);
  cast_bf16_k<<<(294912+255)/256, 256, 0, stream>>>(fc_attn_w, wAb, 294912);
  cat_w3<<<1536, 64, 0, stream>>>(w_ih, wIb3);
  cast_bf16_k<<<(557056+255)/256, 256, 0, stream>>>(fc_final_w, wFb, 557056);

  // history = tanh(histcat @ fc_attn_w^T + b) -> bf16 H
  gemm_bt<1><<<dim3(512,8), 256, 0, stream>>>(histcat, wAb, fc_attn_b, nullptr, Hb, 32768, 512, 576);
  transpose_k<<<dim3(16,1024), 256, 0, stream>>>(Hb, Htb, 32768, 512);
  // gi = x @ w_ih^T + b_ih (hi/lo split, K=1728) -> fp32
  gemm_bt<0><<<dim3(64,24), 256, 0, stream>>>(xcat3, wIb3, b_ih, gi, nullptr, 4096, 1536, 1728);
  // sequential GRU over 4096 steps; writes q (bf16) into outcat cols 0..511
  gru_scan<<<64, 64, 0, stream>>>(gi, w_hh, b_hh, ring, outc);
  // softmax stats
  attn_stats<<<dim3(32,16), 256, 0, stream>>>(outc, Hb, mp, lp);
  stats_combine<<<32, 64, 0, stream>>>(mp, lp, mr, lr);
  // context partials + reduce (writes outcat cols 512..1023)
  attn_ctx<<<dim3(32,8), 256, 0, stream>>>(outc, Hb, Htb, mr, ctxpart);
  ctx_reduce<<<4096, 256, 0, stream>>>(ctxpart, lr, outc);
  // uid embedding (outcat cols 1024..1087)
  uid_gather<<<2048, 64, 0, stream>>>(uid, emb_uid, outc);
  // final linear + log_softmax
  gemm_bt<0><<<dim3(32,8), 256, 0, stream>>>(outc, wFb, fc_final_b, y, nullptr, 2048, 512, 1088);
  log_softmax_k<<<2048, 64, 0, stream>>>(y, out);
}